// Round 4
// baseline (2033.370 us; speedup 1.0000x reference)
//
#include <hip/hip_runtime.h>

// GraphSAGE 2-layer: logits = meanAgg(relu(meanAgg(x@W1)) @ W2)
// N=100000, E=1600000, D_IN=128, D_H=128, D_OUT=64, all fp32.
//
// R2: 3-phase parallel scan (was 280us single-block).
// R3: agg gather x4 unroll (independent chains); gemm k-blocked float4 LDS.
// R4: gemm occupancy fix: 1024-thr blocks, 128-row tiles (gemm1 128KB LDS
//     -> 16 waves/CU = 4/SIMD, was 1/SIMD at 97KB/256thr). Degree/cursor
//     counters padded to 1 per 64B line (kills cross-XCD false sharing on
//     atomic lines); single pc[] array reused degree->cursor.

#define DIN 128
#define DH 128
#define DOUT 64
#define PAD 16   // ints per counter line

#define SCAN_TPB 256
#define SCAN_EPT 4
#define SCAN_CHUNK (SCAN_TPB * SCAN_EPT)

__global__ __launch_bounds__(256) void k_degree(const int* __restrict__ row,
                                                int* __restrict__ pc, int E) {
    int e = blockIdx.x * blockDim.x + threadIdx.x;
    if (e < E) atomicAdd(&pc[(size_t)row[e] * PAD], 1);
}

__global__ __launch_bounds__(SCAN_TPB) void k_scan_part(const int* __restrict__ pc,
                                                        int* __restrict__ bsums, int n) {
    __shared__ int sh[SCAN_TPB];
    int t = threadIdx.x;
    int base = blockIdx.x * SCAN_CHUNK + t * SCAN_EPT;
    int s = 0;
#pragma unroll
    for (int i = 0; i < SCAN_EPT; ++i) {
        int idx = base + i;
        if (idx < n) s += pc[(size_t)idx * PAD];
    }
    sh[t] = s;
    __syncthreads();
    for (int d = SCAN_TPB / 2; d > 0; d >>= 1) {
        if (t < d) sh[t] += sh[t + d];
        __syncthreads();
    }
    if (t == 0) bsums[blockIdx.x] = sh[0];
}

__global__ __launch_bounds__(128) void k_scan_blk(int* __restrict__ bsums, int nb) {
    __shared__ int sh[128];
    int t = threadIdx.x;
    sh[t] = (t < nb) ? bsums[t] : 0;
    __syncthreads();
    for (int d = 1; d < 128; d <<= 1) {
        int v = (t >= d) ? sh[t - d] : 0;
        __syncthreads();
        sh[t] += v;
        __syncthreads();
    }
    if (t < nb) bsums[t] = (t == 0) ? 0 : sh[t - 1];
}

// Reads degree from pc, overwrites pc with cursor start; emits compact
// offs/degc/invdeg.
__global__ __launch_bounds__(SCAN_TPB) void k_scan_final(int* __restrict__ pc,
                                                         const int* __restrict__ bsums,
                                                         int* __restrict__ offs,
                                                         int* __restrict__ degc,
                                                         float* __restrict__ invdeg, int n) {
    __shared__ int sh[SCAN_TPB];
    int t = threadIdx.x;
    int base = blockIdx.x * SCAN_CHUNK + t * SCAN_EPT;
    int d0[SCAN_EPT];
    int s = 0;
#pragma unroll
    for (int i = 0; i < SCAN_EPT; ++i) {
        int idx = base + i;
        d0[i] = (idx < n) ? pc[(size_t)idx * PAD] : 0;
        s += d0[i];
    }
    sh[t] = s;
    __syncthreads();
    for (int d = 1; d < SCAN_TPB; d <<= 1) {
        int v = (t >= d) ? sh[t - d] : 0;
        __syncthreads();
        sh[t] += v;
        __syncthreads();
    }
    int run = bsums[blockIdx.x] + ((t == 0) ? 0 : sh[t - 1]);
#pragma unroll
    for (int i = 0; i < SCAN_EPT; ++i) {
        int idx = base + i;
        if (idx < n) {
            offs[idx] = run;
            degc[idx] = d0[i];
            invdeg[idx] = 1.0f / (float)d0[i];
            pc[(size_t)idx * PAD] = run;   // cursor init
            run += d0[i];
        }
    }
}

__global__ __launch_bounds__(256) void k_scatter(const int* __restrict__ row,
                                                 const int* __restrict__ col,
                                                 int* __restrict__ pc,
                                                 int* __restrict__ csr, int E) {
    int e = blockIdx.x * blockDim.x + threadIdx.x;
    if (e < E) {
        int r = row[e];
        int pos = atomicAdd(&pc[(size_t)r * PAD], 1);
        csr[pos] = col[e];
    }
}

// h1[n,128] = X[n,128] @ W[128,128]. 1024 thr, 128-row x 128-col tile.
// LDS 128KB -> 1 block/CU but 16 waves = 4 waves/SIMD.
__global__ __launch_bounds__(1024) void k_gemm1(const float* __restrict__ X,
                                                const float* __restrict__ W,
                                                float* __restrict__ H, int n) {
    __shared__ float ws[128 * 128];     // 64KB
    __shared__ float xs[128][128];      // 64KB (x-reads are broadcast; no pad needed)
    int tid = threadIdx.x;
    int r0 = blockIdx.x * 128;

    for (int i = tid; i < 128 * 128 / 4; i += 1024)
        ((float4*)ws)[i] = ((const float4*)W)[i];
    for (int i = tid; i < 128 * 32; i += 1024) {
        int r = i >> 5, c4 = i & 31;
        float4 v = make_float4(0.f, 0.f, 0.f, 0.f);
        if (r0 + r < n) v = ((const float4*)X)[(size_t)(r0 + r) * 32 + c4];
        *(float4*)&xs[r][c4 * 4] = v;
    }
    __syncthreads();

    int cg = tid & 31;   // cols cg*4..+3
    int rg = tid >> 5;   // rows rg*4..+3
    float acc[4][4];
#pragma unroll
    for (int r = 0; r < 4; ++r)
#pragma unroll
        for (int c = 0; c < 4; ++c) acc[r][c] = 0.f;

    const float4* ws4 = (const float4*)ws;   // 128 rows x 32 float4
    for (int k4 = 0; k4 < 32; ++k4) {
        float4 w0 = ws4[(k4 * 4 + 0) * 32 + cg];
        float4 w1 = ws4[(k4 * 4 + 1) * 32 + cg];
        float4 w2 = ws4[(k4 * 4 + 2) * 32 + cg];
        float4 w3 = ws4[(k4 * 4 + 3) * 32 + cg];
#pragma unroll
        for (int r = 0; r < 4; ++r) {
            float4 xv = *(const float4*)&xs[rg * 4 + r][k4 * 4];
            acc[r][0] += xv.x * w0.x + xv.y * w1.x + xv.z * w2.x + xv.w * w3.x;
            acc[r][1] += xv.x * w0.y + xv.y * w1.y + xv.z * w2.y + xv.w * w3.y;
            acc[r][2] += xv.x * w0.z + xv.y * w1.z + xv.z * w2.z + xv.w * w3.z;
            acc[r][3] += xv.x * w0.w + xv.y * w1.w + xv.z * w2.w + xv.w * w3.w;
        }
    }
#pragma unroll
    for (int r = 0; r < 4; ++r) {
        int rr = r0 + rg * 4 + r;
        if (rr < n)
            *(float4*)&H[(size_t)rr * 128 + cg * 4] = *(float4*)&acc[r][0];
    }
}

// h2[n,64] = X[n,128] @ W[128,64]. 1024 thr, 128-row x 64-col tile, 96KB LDS.
__global__ __launch_bounds__(1024) void k_gemm2(const float* __restrict__ X,
                                                const float* __restrict__ W,
                                                float* __restrict__ H, int n) {
    __shared__ float ws[128 * 64];      // 32KB
    __shared__ float xs[128][128];      // 64KB
    int tid = threadIdx.x;
    int r0 = blockIdx.x * 128;

    for (int i = tid; i < 128 * 64 / 4; i += 1024)
        ((float4*)ws)[i] = ((const float4*)W)[i];
    for (int i = tid; i < 128 * 32; i += 1024) {
        int r = i >> 5, c4 = i & 31;
        float4 v = make_float4(0.f, 0.f, 0.f, 0.f);
        if (r0 + r < n) v = ((const float4*)X)[(size_t)(r0 + r) * 32 + c4];
        *(float4*)&xs[r][c4 * 4] = v;
    }
    __syncthreads();

    int cg = tid & 15;   // cols cg*4..+3 (64 cols)
    int rg = tid >> 4;   // 0..63, rows rg*2..+1
    float acc[2][4];
#pragma unroll
    for (int r = 0; r < 2; ++r)
#pragma unroll
        for (int c = 0; c < 4; ++c) acc[r][c] = 0.f;

    const float4* ws4 = (const float4*)ws;   // 128 rows x 16 float4
    for (int k4 = 0; k4 < 32; ++k4) {
        float4 w0 = ws4[(k4 * 4 + 0) * 16 + cg];
        float4 w1 = ws4[(k4 * 4 + 1) * 16 + cg];
        float4 w2 = ws4[(k4 * 4 + 2) * 16 + cg];
        float4 w3 = ws4[(k4 * 4 + 3) * 16 + cg];
#pragma unroll
        for (int r = 0; r < 2; ++r) {
            float4 xv = *(const float4*)&xs[rg * 2 + r][k4 * 4];
            acc[r][0] += xv.x * w0.x + xv.y * w1.x + xv.z * w2.x + xv.w * w3.x;
            acc[r][1] += xv.x * w0.y + xv.y * w1.y + xv.z * w2.y + xv.w * w3.y;
            acc[r][2] += xv.x * w0.z + xv.y * w1.z + xv.z * w2.z + xv.w * w3.z;
            acc[r][3] += xv.x * w0.w + xv.y * w1.w + xv.z * w2.w + xv.w * w3.w;
        }
    }
#pragma unroll
    for (int r = 0; r < 2; ++r) {
        int rr = r0 + rg * 2 + r;
        if (rr < n)
            *(float4*)&H[(size_t)rr * 64 + cg * 4] = *(float4*)&acc[r][0];
    }
}

// agg1: Hout[row] = relu( (1/deg) * sum_{c in csr[row]} H1[c] ), D=128.
__global__ __launch_bounds__(256) void k_agg1(const float* __restrict__ H1,
                                              const int* __restrict__ offs,
                                              const int* __restrict__ degc,
                                              const float* __restrict__ invdeg,
                                              const int* __restrict__ csr,
                                              float* __restrict__ Hout, int n) {
    int wave = threadIdx.x >> 6, lane = threadIdx.x & 63;
    int row = blockIdx.x * 4 + wave;
    if (row >= n) return;
    int start = offs[row], d = degc[row];
    float a0 = 0.f, a1 = 0.f, b0 = 0.f, b1 = 0.f;
    float c0 = 0.f, c1 = 0.f, e0 = 0.f, e1 = 0.f;
    int i = 0;
    for (; i + 4 <= d; i += 4) {
        int n0 = csr[start + i + 0];
        int n1 = csr[start + i + 1];
        int n2 = csr[start + i + 2];
        int n3 = csr[start + i + 3];
        float2 v0 = *(const float2*)&H1[(size_t)n0 * 128 + lane * 2];
        float2 v1 = *(const float2*)&H1[(size_t)n1 * 128 + lane * 2];
        float2 v2 = *(const float2*)&H1[(size_t)n2 * 128 + lane * 2];
        float2 v3 = *(const float2*)&H1[(size_t)n3 * 128 + lane * 2];
        a0 += v0.x; a1 += v0.y;
        b0 += v1.x; b1 += v1.y;
        c0 += v2.x; c1 += v2.y;
        e0 += v3.x; e1 += v3.y;
    }
    for (; i < d; ++i) {
        int c = csr[start + i];
        float2 v = *(const float2*)&H1[(size_t)c * 128 + lane * 2];
        a0 += v.x; a1 += v.y;
    }
    float inv = invdeg[row];
    float r0 = fmaxf((a0 + b0 + c0 + e0) * inv, 0.f);
    float r1 = fmaxf((a1 + b1 + c1 + e1) * inv, 0.f);
    *(float2*)&Hout[(size_t)row * 128 + lane * 2] = make_float2(r0, r1);
}

// agg2: Out[row] = (1/deg) * sum H2[c], D=64.
__global__ __launch_bounds__(256) void k_agg2(const float* __restrict__ H2,
                                              const int* __restrict__ offs,
                                              const int* __restrict__ degc,
                                              const float* __restrict__ invdeg,
                                              const int* __restrict__ csr,
                                              float* __restrict__ Out, int n) {
    int wave = threadIdx.x >> 6, lane = threadIdx.x & 63;
    int row = blockIdx.x * 4 + wave;
    if (row >= n) return;
    int start = offs[row], d = degc[row];
    float a = 0.f, b = 0.f, c = 0.f, e = 0.f;
    int i = 0;
    for (; i + 4 <= d; i += 4) {
        int n0 = csr[start + i + 0];
        int n1 = csr[start + i + 1];
        int n2 = csr[start + i + 2];
        int n3 = csr[start + i + 3];
        a += H2[(size_t)n0 * 64 + lane];
        b += H2[(size_t)n1 * 64 + lane];
        c += H2[(size_t)n2 * 64 + lane];
        e += H2[(size_t)n3 * 64 + lane];
    }
    for (; i < d; ++i) {
        int n0 = csr[start + i];
        a += H2[(size_t)n0 * 64 + lane];
    }
    Out[(size_t)row * 64 + lane] = (a + b + c + e) * invdeg[row];
}

extern "C" void kernel_launch(void* const* d_in, const int* in_sizes, int n_in,
                              void* d_out, int out_size, void* d_ws, size_t ws_size,
                              hipStream_t stream) {
    const float* x    = (const float*)d_in[0];
    const float* W1   = (const float*)d_in[1];
    const float* W2   = (const float*)d_in[2];
    const int*   erow = (const int*)d_in[3];
    const int*   ecol = (const int*)d_in[4];
    const int N = in_sizes[0] / DIN;
    const int E = in_sizes[3];

    size_t o = 0;
    auto take = [&](size_t nbytes) {
        void* p = (char*)d_ws + o;
        o += (nbytes + 255) & ~(size_t)255;
        return p;
    };
    int nscan = (N + SCAN_CHUNK - 1) / SCAN_CHUNK;
    int*   pc     = (int*)take((size_t)N * PAD * 4);   // padded degree->cursor
    int*   offs   = (int*)take((size_t)N * 4);
    int*   degc   = (int*)take((size_t)N * 4);
    float* invdeg = (float*)take((size_t)N * 4);
    int*   bsums  = (int*)take((size_t)nscan * 4);
    int*   csr    = (int*)take((size_t)E * 4);
    float* h1     = (float*)take((size_t)N * DH * 4);
    float* h      = (float*)take((size_t)N * DH * 4);
    float* h2     = h1;   // gemm2 output reuses h1 (dead after agg1)

    hipMemsetAsync(pc, 0, (size_t)N * PAD * 4, stream);
    k_degree<<<(E + 255) / 256, 256, 0, stream>>>(erow, pc, E);
    k_scan_part<<<nscan, SCAN_TPB, 0, stream>>>(pc, bsums, N);
    k_scan_blk<<<1, 128, 0, stream>>>(bsums, nscan);
    k_scan_final<<<nscan, SCAN_TPB, 0, stream>>>(pc, bsums, offs, degc, invdeg, N);
    k_scatter<<<(E + 255) / 256, 256, 0, stream>>>(erow, ecol, pc, csr, E);
    k_gemm1<<<(N + 127) / 128, 1024, 0, stream>>>(x, W1, h1, N);
    k_agg1<<<(N + 3) / 4, 256, 0, stream>>>(h1, offs, degc, invdeg, csr, h, N);
    k_gemm2<<<(N + 127) / 128, 1024, 0, stream>>>(h, W2, h2, N);
    k_agg2<<<(N + 3) / 4, 256, 0, stream>>>(h2, offs, degc, invdeg, csr, (float*)d_out, N);
}

// Round 5
// 545.139 us; speedup vs baseline: 3.7300x; 3.7300x over previous
//
#include <hip/hip_runtime.h>

// GraphSAGE 2-layer: logits = meanAgg(relu(meanAgg(x@W1)) @ W2)
// N=100000, E=1600000, D_IN=128, D_H=128, D_OUT=64, all fp32.
//
// R2: 3-phase parallel scan (was 280us single-block).
// R3: agg gather x4 unroll; gemm k-blocked float4 LDS reads.
// R4: FAILED - 1024-thr gemm blocks capped VGPR at 64 -> scratch spills
//     (4.18GB HBM traffic on gemm2). Reverted.
// R5: gemm occupancy via LESS LDS: only X tile staged (34KB), W read from
//     global (L2-hot, coalesced float4). 256 thr, R3 register tiling.
//     Padded atomic counters (1/64B line) kept from R4.

#define DIN 128
#define DH 128
#define DOUT 64
#define PAD 16   // ints per counter line

#define SCAN_TPB 256
#define SCAN_EPT 4
#define SCAN_CHUNK (SCAN_TPB * SCAN_EPT)

__global__ __launch_bounds__(256) void k_degree(const int* __restrict__ row,
                                                int* __restrict__ pc, int E) {
    int e = blockIdx.x * blockDim.x + threadIdx.x;
    if (e < E) atomicAdd(&pc[(size_t)row[e] * PAD], 1);
}

__global__ __launch_bounds__(SCAN_TPB) void k_scan_part(const int* __restrict__ pc,
                                                        int* __restrict__ bsums, int n) {
    __shared__ int sh[SCAN_TPB];
    int t = threadIdx.x;
    int base = blockIdx.x * SCAN_CHUNK + t * SCAN_EPT;
    int s = 0;
#pragma unroll
    for (int i = 0; i < SCAN_EPT; ++i) {
        int idx = base + i;
        if (idx < n) s += pc[(size_t)idx * PAD];
    }
    sh[t] = s;
    __syncthreads();
    for (int d = SCAN_TPB / 2; d > 0; d >>= 1) {
        if (t < d) sh[t] += sh[t + d];
        __syncthreads();
    }
    if (t == 0) bsums[blockIdx.x] = sh[0];
}

__global__ __launch_bounds__(128) void k_scan_blk(int* __restrict__ bsums, int nb) {
    __shared__ int sh[128];
    int t = threadIdx.x;
    sh[t] = (t < nb) ? bsums[t] : 0;
    __syncthreads();
    for (int d = 1; d < 128; d <<= 1) {
        int v = (t >= d) ? sh[t - d] : 0;
        __syncthreads();
        sh[t] += v;
        __syncthreads();
    }
    if (t < nb) bsums[t] = (t == 0) ? 0 : sh[t - 1];
}

__global__ __launch_bounds__(SCAN_TPB) void k_scan_final(int* __restrict__ pc,
                                                         const int* __restrict__ bsums,
                                                         int* __restrict__ offs,
                                                         int* __restrict__ degc,
                                                         float* __restrict__ invdeg, int n) {
    __shared__ int sh[SCAN_TPB];
    int t = threadIdx.x;
    int base = blockIdx.x * SCAN_CHUNK + t * SCAN_EPT;
    int d0[SCAN_EPT];
    int s = 0;
#pragma unroll
    for (int i = 0; i < SCAN_EPT; ++i) {
        int idx = base + i;
        d0[i] = (idx < n) ? pc[(size_t)idx * PAD] : 0;
        s += d0[i];
    }
    sh[t] = s;
    __syncthreads();
    for (int d = 1; d < SCAN_TPB; d <<= 1) {
        int v = (t >= d) ? sh[t - d] : 0;
        __syncthreads();
        sh[t] += v;
        __syncthreads();
    }
    int run = bsums[blockIdx.x] + ((t == 0) ? 0 : sh[t - 1]);
#pragma unroll
    for (int i = 0; i < SCAN_EPT; ++i) {
        int idx = base + i;
        if (idx < n) {
            offs[idx] = run;
            degc[idx] = d0[i];
            invdeg[idx] = 1.0f / (float)d0[i];
            pc[(size_t)idx * PAD] = run;   // cursor init
            run += d0[i];
        }
    }
}

__global__ __launch_bounds__(256) void k_scatter(const int* __restrict__ row,
                                                 const int* __restrict__ col,
                                                 int* __restrict__ pc,
                                                 int* __restrict__ csr, int E) {
    int e = blockIdx.x * blockDim.x + threadIdx.x;
    if (e < E) {
        int r = row[e];
        int pos = atomicAdd(&pc[(size_t)r * PAD], 1);
        csr[pos] = col[e];
    }
}

// h1[n,128] = X[n,128] @ W[128,128]. 256 thr, 64-row x 128-col tile.
// Only X in LDS (34KB); W from global (L2-hot, coalesced).
__global__ __launch_bounds__(256) void k_gemm1(const float* __restrict__ X,
                                               const float* __restrict__ W,
                                               float* __restrict__ H, int n) {
    __shared__ float xs[64][132];       // 33.8KB; 528B row pitch
    int tid = threadIdx.x;
    int r0 = blockIdx.x * 64;

    for (int i = tid; i < 64 * 32; i += 256) {
        int r = i >> 5, c4 = i & 31;
        float4 v = make_float4(0.f, 0.f, 0.f, 0.f);
        if (r0 + r < n) v = ((const float4*)X)[(size_t)(r0 + r) * 32 + c4];
        *(float4*)&xs[r][c4 * 4] = v;
    }
    __syncthreads();

    int cg = tid & 31;   // cols cg*4..+3
    int rg = tid >> 5;   // rows rg*8..+7
    float acc[8][4];
#pragma unroll
    for (int r = 0; r < 8; ++r)
#pragma unroll
        for (int c = 0; c < 4; ++c) acc[r][c] = 0.f;

    const float4* W4 = (const float4*)W;   // 128 rows x 32 float4
#pragma unroll 2
    for (int k4 = 0; k4 < 32; ++k4) {
        float4 w0 = W4[(k4 * 4 + 0) * 32 + cg];
        float4 w1 = W4[(k4 * 4 + 1) * 32 + cg];
        float4 w2 = W4[(k4 * 4 + 2) * 32 + cg];
        float4 w3 = W4[(k4 * 4 + 3) * 32 + cg];
#pragma unroll
        for (int r = 0; r < 8; ++r) {
            float4 xv = *(const float4*)&xs[rg * 8 + r][k4 * 4];
            acc[r][0] += xv.x * w0.x + xv.y * w1.x + xv.z * w2.x + xv.w * w3.x;
            acc[r][1] += xv.x * w0.y + xv.y * w1.y + xv.z * w2.y + xv.w * w3.y;
            acc[r][2] += xv.x * w0.z + xv.y * w1.z + xv.z * w2.z + xv.w * w3.z;
            acc[r][3] += xv.x * w0.w + xv.y * w1.w + xv.z * w2.w + xv.w * w3.w;
        }
    }
#pragma unroll
    for (int r = 0; r < 8; ++r) {
        int rr = r0 + rg * 8 + r;
        if (rr < n)
            *(float4*)&H[(size_t)rr * 128 + cg * 4] = *(float4*)&acc[r][0];
    }
}

// h2[n,64] = X[n,128] @ W[128,64]. 256 thr, 64-row x 64-col tile.
__global__ __launch_bounds__(256) void k_gemm2(const float* __restrict__ X,
                                               const float* __restrict__ W,
                                               float* __restrict__ H, int n) {
    __shared__ float xs[64][132];
    int tid = threadIdx.x;
    int r0 = blockIdx.x * 64;

    for (int i = tid; i < 64 * 32; i += 256) {
        int r = i >> 5, c4 = i & 31;
        float4 v = make_float4(0.f, 0.f, 0.f, 0.f);
        if (r0 + r < n) v = ((const float4*)X)[(size_t)(r0 + r) * 32 + c4];
        *(float4*)&xs[r][c4 * 4] = v;
    }
    __syncthreads();

    int cg = tid & 15;   // cols cg*4..+3 (64 cols)
    int rg = tid >> 4;   // rows rg*4..+3
    float acc[4][4];
#pragma unroll
    for (int r = 0; r < 4; ++r)
#pragma unroll
        for (int c = 0; c < 4; ++c) acc[r][c] = 0.f;

    const float4* W4 = (const float4*)W;   // 128 rows x 16 float4
#pragma unroll 2
    for (int k4 = 0; k4 < 32; ++k4) {
        float4 w0 = W4[(k4 * 4 + 0) * 16 + cg];
        float4 w1 = W4[(k4 * 4 + 1) * 16 + cg];
        float4 w2 = W4[(k4 * 4 + 2) * 16 + cg];
        float4 w3 = W4[(k4 * 4 + 3) * 16 + cg];
#pragma unroll
        for (int r = 0; r < 4; ++r) {
            float4 xv = *(const float4*)&xs[rg * 4 + r][k4 * 4];
            acc[r][0] += xv.x * w0.x + xv.y * w1.x + xv.z * w2.x + xv.w * w3.x;
            acc[r][1] += xv.x * w0.y + xv.y * w1.y + xv.z * w2.y + xv.w * w3.y;
            acc[r][2] += xv.x * w0.z + xv.y * w1.z + xv.z * w2.z + xv.w * w3.z;
            acc[r][3] += xv.x * w0.w + xv.y * w1.w + xv.z * w2.w + xv.w * w3.w;
        }
    }
#pragma unroll
    for (int r = 0; r < 4; ++r) {
        int rr = r0 + rg * 4 + r;
        if (rr < n)
            *(float4*)&H[(size_t)rr * 64 + cg * 4] = *(float4*)&acc[r][0];
    }
}

// agg1: Hout[row] = relu( (1/deg) * sum_{c in csr[row]} H1[c] ), D=128.
__global__ __launch_bounds__(256) void k_agg1(const float* __restrict__ H1,
                                              const int* __restrict__ offs,
                                              const int* __restrict__ degc,
                                              const float* __restrict__ invdeg,
                                              const int* __restrict__ csr,
                                              float* __restrict__ Hout, int n) {
    int wave = threadIdx.x >> 6, lane = threadIdx.x & 63;
    int row = blockIdx.x * 4 + wave;
    if (row >= n) return;
    int start = offs[row], d = degc[row];
    float a0 = 0.f, a1 = 0.f, b0 = 0.f, b1 = 0.f;
    float c0 = 0.f, c1 = 0.f, e0 = 0.f, e1 = 0.f;
    int i = 0;
    for (; i + 4 <= d; i += 4) {
        int n0 = csr[start + i + 0];
        int n1 = csr[start + i + 1];
        int n2 = csr[start + i + 2];
        int n3 = csr[start + i + 3];
        float2 v0 = *(const float2*)&H1[(size_t)n0 * 128 + lane * 2];
        float2 v1 = *(const float2*)&H1[(size_t)n1 * 128 + lane * 2];
        float2 v2 = *(const float2*)&H1[(size_t)n2 * 128 + lane * 2];
        float2 v3 = *(const float2*)&H1[(size_t)n3 * 128 + lane * 2];
        a0 += v0.x; a1 += v0.y;
        b0 += v1.x; b1 += v1.y;
        c0 += v2.x; c1 += v2.y;
        e0 += v3.x; e1 += v3.y;
    }
    for (; i < d; ++i) {
        int c = csr[start + i];
        float2 v = *(const float2*)&H1[(size_t)c * 128 + lane * 2];
        a0 += v.x; a1 += v.y;
    }
    float inv = invdeg[row];
    float r0 = fmaxf((a0 + b0 + c0 + e0) * inv, 0.f);
    float r1 = fmaxf((a1 + b1 + c1 + e1) * inv, 0.f);
    *(float2*)&Hout[(size_t)row * 128 + lane * 2] = make_float2(r0, r1);
}

// agg2: Out[row] = (1/deg) * sum H2[c], D=64.
__global__ __launch_bounds__(256) void k_agg2(const float* __restrict__ H2,
                                              const int* __restrict__ offs,
                                              const int* __restrict__ degc,
                                              const float* __restrict__ invdeg,
                                              const int* __restrict__ csr,
                                              float* __restrict__ Out, int n) {
    int wave = threadIdx.x >> 6, lane = threadIdx.x & 63;
    int row = blockIdx.x * 4 + wave;
    if (row >= n) return;
    int start = offs[row], d = degc[row];
    float a = 0.f, b = 0.f, c = 0.f, e = 0.f;
    int i = 0;
    for (; i + 4 <= d; i += 4) {
        int n0 = csr[start + i + 0];
        int n1 = csr[start + i + 1];
        int n2 = csr[start + i + 2];
        int n3 = csr[start + i + 3];
        a += H2[(size_t)n0 * 64 + lane];
        b += H2[(size_t)n1 * 64 + lane];
        c += H2[(size_t)n2 * 64 + lane];
        e += H2[(size_t)n3 * 64 + lane];
    }
    for (; i < d; ++i) {
        int n0 = csr[start + i];
        a += H2[(size_t)n0 * 64 + lane];
    }
    Out[(size_t)row * 64 + lane] = (a + b + c + e) * invdeg[row];
}

extern "C" void kernel_launch(void* const* d_in, const int* in_sizes, int n_in,
                              void* d_out, int out_size, void* d_ws, size_t ws_size,
                              hipStream_t stream) {
    const float* x    = (const float*)d_in[0];
    const float* W1   = (const float*)d_in[1];
    const float* W2   = (const float*)d_in[2];
    const int*   erow = (const int*)d_in[3];
    const int*   ecol = (const int*)d_in[4];
    const int N = in_sizes[0] / DIN;
    const int E = in_sizes[3];

    size_t o = 0;
    auto take = [&](size_t nbytes) {
        void* p = (char*)d_ws + o;
        o += (nbytes + 255) & ~(size_t)255;
        return p;
    };
    int nscan = (N + SCAN_CHUNK - 1) / SCAN_CHUNK;
    int*   pc     = (int*)take((size_t)N * PAD * 4);   // padded degree->cursor
    int*   offs   = (int*)take((size_t)N * 4);
    int*   degc   = (int*)take((size_t)N * 4);
    float* invdeg = (float*)take((size_t)N * 4);
    int*   bsums  = (int*)take((size_t)nscan * 4);
    int*   csr    = (int*)take((size_t)E * 4);
    float* h1     = (float*)take((size_t)N * DH * 4);
    float* h      = (float*)take((size_t)N * DH * 4);
    float* h2     = h1;   // gemm2 output reuses h1 (dead after agg1)

    hipMemsetAsync(pc, 0, (size_t)N * PAD * 4, stream);
    k_degree<<<(E + 255) / 256, 256, 0, stream>>>(erow, pc, E);
    k_scan_part<<<nscan, SCAN_TPB, 0, stream>>>(pc, bsums, N);
    k_scan_blk<<<1, 128, 0, stream>>>(bsums, nscan);
    k_scan_final<<<nscan, SCAN_TPB, 0, stream>>>(pc, bsums, offs, degc, invdeg, N);
    k_scatter<<<(E + 255) / 256, 256, 0, stream>>>(erow, ecol, pc, csr, E);
    k_gemm1<<<(N + 63) / 64, 256, 0, stream>>>(x, W1, h1, N);
    k_agg1<<<(N + 3) / 4, 256, 0, stream>>>(h1, offs, degc, invdeg, csr, h, N);
    k_gemm2<<<(N + 63) / 64, 256, 0, stream>>>(h, W2, h2, N);
    k_agg2<<<(N + 3) / 4, 256, 0, stream>>>(h2, offs, degc, invdeg, csr, (float*)d_out, N);
}

// Round 6
// 504.247 us; speedup vs baseline: 4.0325x; 1.0811x over previous
//
#include <hip/hip_runtime.h>

// GraphSAGE 2-layer: logits = meanAgg(relu(meanAgg(x@W1)) @ W2)
// N=100000, E=1600000, D_IN=128, D_H=128, D_OUT=64, all fp32.
//
// R2: 3-phase parallel scan. R3: agg x4 unroll; gemm float4 LDS reads.
// R4: FAILED - 1024-thr gemm -> VGPR cap 64 -> spills (4GB traffic).
// R5: gemm W from global (L2-hot), only X tile in LDS. Counter padding
//     FAILED (scatter 122->140us; contention wasn't the cost).
// R6: CSR build rewritten as 2-level counting sort, zero global atomics.
//     R5 scatter was bound by random partial-line writes (WRITE_SIZE
//     105MB = 1.6M x 64B masked HBM transactions). Now every csr/bucket
//     region is written by exactly one block in dense runs.
//     Requires: col < 2^17, bucket rows = 512, nb<=256 (N=100K -> nb=196).

#define DIN 128
#define DH 128
#define DOUT 64

#define BSH 9                    // 512 rows per bucket
#define COLB 17                  // col fits 17 bits (N=100000 < 2^17)
#define COLM ((1 << COLB) - 1)
#define LRM ((1 << BSH) - 1)
#define CHUNK 8192               // edges per pass-1/3 block
#define CH_PT 32                 // edges per thread

// Pass 1: per-chunk LDS histogram over buckets -> HT[bucket][chunk].
__global__ __launch_bounds__(256) void k_hist(const int* __restrict__ row,
                                              int* __restrict__ HT,
                                              int E, int nb, int nch) {
    __shared__ int h[512];
    int t = threadIdx.x, c = blockIdx.x;
    for (int i = t; i < nb; i += 256) h[i] = 0;
    __syncthreads();
    int base = c * CHUNK;
#pragma unroll
    for (int i = 0; i < CH_PT; ++i) {
        int e = base + i * 256 + t;
        if (e < E) atomicAdd(&h[row[e] >> BSH], 1);
    }
    __syncthreads();
    for (int i = t; i < nb; i += 256) HT[(size_t)i * nch + c] = h[i];
}

// Pass 2: one block. Thread t serial-scans bucket t's chunk row (in-place ->
// local starts), then 256-wide exclusive scan of bucket totals -> bases.
__global__ __launch_bounds__(256) void k_hscan(int* __restrict__ HT,
                                               int* __restrict__ bucketBase,
                                               int nb, int nch, int E) {
    __shared__ int sh[256];
    int t = threadIdx.x;
    int run = 0;
    if (t < nb) {
        for (int c = 0; c < nch; ++c) {
            int v = HT[(size_t)t * nch + c];
            HT[(size_t)t * nch + c] = run;
            run += v;
        }
    }
    sh[t] = (t < nb) ? run : 0;
    __syncthreads();
    for (int d = 1; d < 256; d <<= 1) {
        int v = (t >= d) ? sh[t - d] : 0;
        __syncthreads();
        sh[t] += v;
        __syncthreads();
    }
    int base = (t == 0) ? 0 : sh[t - 1];
    if (t < nb) {
        bucketBase[t] = base;
        for (int c = 0; c < nch; ++c) HT[(size_t)t * nch + c] += base;
    }
    if (t == 0) bucketBase[nb] = E;
}

// Pass 3: chunk c scatters its edges into per-(chunk,bucket) contiguous runs.
// packed = (localrow << COLB) | col. LDS cursors only; writes are dense runs
// owned by this block alone.
__global__ __launch_bounds__(256) void k_part(const int* __restrict__ row,
                                              const int* __restrict__ col,
                                              const int* __restrict__ HT,
                                              int* __restrict__ packed,
                                              int E, int nb, int nch) {
    __shared__ int cur[512];
    int t = threadIdx.x, c = blockIdx.x;
    for (int i = t; i < nb; i += 256) cur[i] = HT[(size_t)i * nch + c];
    __syncthreads();
    int base = c * CHUNK;
#pragma unroll
    for (int i = 0; i < CH_PT; ++i) {
        int e = base + i * 256 + t;
        if (e < E) {
            int r = row[e], cc = col[e];
            int b = r >> BSH;
            int pos = atomicAdd(&cur[b], 1);
            packed[pos] = ((r & LRM) << COLB) | cc;
        }
    }
}

// Pass 4: bucket b builds its 512-row CSR segment: LDS hist + scan ->
// offs/degc/invdeg, then csr scatter within [lo,hi) (one writer block).
__global__ __launch_bounds__(256) void k_build(const int* __restrict__ packed,
                                               const int* __restrict__ bucketBase,
                                               int* __restrict__ csr,
                                               int* __restrict__ offs,
                                               int* __restrict__ degc,
                                               float* __restrict__ invdeg,
                                               int N, int nb) {
    __shared__ int hist[512], scn[512], part[256];
    int t = threadIdx.x, b = blockIdx.x;
    int lo = bucketBase[b], hi = bucketBase[b + 1];
    int base_row = b << BSH;
    int nloc = N - base_row; if (nloc > 512) nloc = 512;
    hist[t] = 0; hist[t + 256] = 0;
    __syncthreads();
    for (int e = lo + t; e < hi; e += 256)
        atomicAdd(&hist[packed[e] >> COLB], 1);
    __syncthreads();
    int a = hist[2 * t], b2 = hist[2 * t + 1];
    part[t] = a + b2;
    __syncthreads();
    for (int d = 1; d < 256; d <<= 1) {
        int v = (t >= d) ? part[t - d] : 0;
        __syncthreads();
        part[t] += v;
        __syncthreads();
    }
    int bp = (t == 0) ? 0 : part[t - 1];
    scn[2 * t] = bp;
    scn[2 * t + 1] = bp + a;
    __syncthreads();
    for (int i = t; i < nloc; i += 256) {
        int r = base_row + i;
        offs[r] = lo + scn[i];
        int d = hist[i];
        degc[r] = d;
        invdeg[r] = 1.0f / (float)d;
    }
    __syncthreads();
    for (int e = lo + t; e < hi; e += 256) {
        int p = packed[e];
        int pos = lo + atomicAdd(&scn[p >> COLB], 1);
        csr[pos] = p & COLM;
    }
}

// h1[n,128] = X[n,128] @ W[128,128]. 256 thr, 64-row x 128-col tile.
// Only X in LDS (34KB); W from global (L2-hot, coalesced).
__global__ __launch_bounds__(256) void k_gemm1(const float* __restrict__ X,
                                               const float* __restrict__ W,
                                               float* __restrict__ H, int n) {
    __shared__ float xs[64][132];
    int tid = threadIdx.x;
    int r0 = blockIdx.x * 64;

    for (int i = tid; i < 64 * 32; i += 256) {
        int r = i >> 5, c4 = i & 31;
        float4 v = make_float4(0.f, 0.f, 0.f, 0.f);
        if (r0 + r < n) v = ((const float4*)X)[(size_t)(r0 + r) * 32 + c4];
        *(float4*)&xs[r][c4 * 4] = v;
    }
    __syncthreads();

    int cg = tid & 31;
    int rg = tid >> 5;
    float acc[8][4];
#pragma unroll
    for (int r = 0; r < 8; ++r)
#pragma unroll
        for (int c = 0; c < 4; ++c) acc[r][c] = 0.f;

    const float4* W4 = (const float4*)W;
#pragma unroll 2
    for (int k4 = 0; k4 < 32; ++k4) {
        float4 w0 = W4[(k4 * 4 + 0) * 32 + cg];
        float4 w1 = W4[(k4 * 4 + 1) * 32 + cg];
        float4 w2 = W4[(k4 * 4 + 2) * 32 + cg];
        float4 w3 = W4[(k4 * 4 + 3) * 32 + cg];
#pragma unroll
        for (int r = 0; r < 8; ++r) {
            float4 xv = *(const float4*)&xs[rg * 8 + r][k4 * 4];
            acc[r][0] += xv.x * w0.x + xv.y * w1.x + xv.z * w2.x + xv.w * w3.x;
            acc[r][1] += xv.x * w0.y + xv.y * w1.y + xv.z * w2.y + xv.w * w3.y;
            acc[r][2] += xv.x * w0.z + xv.y * w1.z + xv.z * w2.z + xv.w * w3.z;
            acc[r][3] += xv.x * w0.w + xv.y * w1.w + xv.z * w2.w + xv.w * w3.w;
        }
    }
#pragma unroll
    for (int r = 0; r < 8; ++r) {
        int rr = r0 + rg * 8 + r;
        if (rr < n)
            *(float4*)&H[(size_t)rr * 128 + cg * 4] = *(float4*)&acc[r][0];
    }
}

// h2[n,64] = X[n,128] @ W[128,64]. 256 thr, 64-row x 64-col tile.
__global__ __launch_bounds__(256) void k_gemm2(const float* __restrict__ X,
                                               const float* __restrict__ W,
                                               float* __restrict__ H, int n) {
    __shared__ float xs[64][132];
    int tid = threadIdx.x;
    int r0 = blockIdx.x * 64;

    for (int i = tid; i < 64 * 32; i += 256) {
        int r = i >> 5, c4 = i & 31;
        float4 v = make_float4(0.f, 0.f, 0.f, 0.f);
        if (r0 + r < n) v = ((const float4*)X)[(size_t)(r0 + r) * 32 + c4];
        *(float4*)&xs[r][c4 * 4] = v;
    }
    __syncthreads();

    int cg = tid & 15;
    int rg = tid >> 4;
    float acc[4][4];
#pragma unroll
    for (int r = 0; r < 4; ++r)
#pragma unroll
        for (int c = 0; c < 4; ++c) acc[r][c] = 0.f;

    const float4* W4 = (const float4*)W;
#pragma unroll 2
    for (int k4 = 0; k4 < 32; ++k4) {
        float4 w0 = W4[(k4 * 4 + 0) * 16 + cg];
        float4 w1 = W4[(k4 * 4 + 1) * 16 + cg];
        float4 w2 = W4[(k4 * 4 + 2) * 16 + cg];
        float4 w3 = W4[(k4 * 4 + 3) * 16 + cg];
#pragma unroll
        for (int r = 0; r < 4; ++r) {
            float4 xv = *(const float4*)&xs[rg * 4 + r][k4 * 4];
            acc[r][0] += xv.x * w0.x + xv.y * w1.x + xv.z * w2.x + xv.w * w3.x;
            acc[r][1] += xv.x * w0.y + xv.y * w1.y + xv.z * w2.y + xv.w * w3.y;
            acc[r][2] += xv.x * w0.z + xv.y * w1.z + xv.z * w2.z + xv.w * w3.z;
            acc[r][3] += xv.x * w0.w + xv.y * w1.w + xv.z * w2.w + xv.w * w3.w;
        }
    }
#pragma unroll
    for (int r = 0; r < 4; ++r) {
        int rr = r0 + rg * 4 + r;
        if (rr < n)
            *(float4*)&H[(size_t)rr * 64 + cg * 4] = *(float4*)&acc[r][0];
    }
}

// agg1: Hout[row] = relu( (1/deg) * sum_{c in csr[row]} H1[c] ), D=128.
__global__ __launch_bounds__(256) void k_agg1(const float* __restrict__ H1,
                                              const int* __restrict__ offs,
                                              const int* __restrict__ degc,
                                              const float* __restrict__ invdeg,
                                              const int* __restrict__ csr,
                                              float* __restrict__ Hout, int n) {
    int wave = threadIdx.x >> 6, lane = threadIdx.x & 63;
    int row = blockIdx.x * 4 + wave;
    if (row >= n) return;
    int start = offs[row], d = degc[row];
    float a0 = 0.f, a1 = 0.f, b0 = 0.f, b1 = 0.f;
    float c0 = 0.f, c1 = 0.f, e0 = 0.f, e1 = 0.f;
    int i = 0;
    for (; i + 4 <= d; i += 4) {
        int n0 = csr[start + i + 0];
        int n1 = csr[start + i + 1];
        int n2 = csr[start + i + 2];
        int n3 = csr[start + i + 3];
        float2 v0 = *(const float2*)&H1[(size_t)n0 * 128 + lane * 2];
        float2 v1 = *(const float2*)&H1[(size_t)n1 * 128 + lane * 2];
        float2 v2 = *(const float2*)&H1[(size_t)n2 * 128 + lane * 2];
        float2 v3 = *(const float2*)&H1[(size_t)n3 * 128 + lane * 2];
        a0 += v0.x; a1 += v0.y;
        b0 += v1.x; b1 += v1.y;
        c0 += v2.x; c1 += v2.y;
        e0 += v3.x; e1 += v3.y;
    }
    for (; i < d; ++i) {
        int c = csr[start + i];
        float2 v = *(const float2*)&H1[(size_t)c * 128 + lane * 2];
        a0 += v.x; a1 += v.y;
    }
    float inv = invdeg[row];
    float r0 = fmaxf((a0 + b0 + c0 + e0) * inv, 0.f);
    float r1 = fmaxf((a1 + b1 + c1 + e1) * inv, 0.f);
    *(float2*)&Hout[(size_t)row * 128 + lane * 2] = make_float2(r0, r1);
}

// agg2: Out[row] = (1/deg) * sum H2[c], D=64.
__global__ __launch_bounds__(256) void k_agg2(const float* __restrict__ H2,
                                              const int* __restrict__ offs,
                                              const int* __restrict__ degc,
                                              const float* __restrict__ invdeg,
                                              const int* __restrict__ csr,
                                              float* __restrict__ Out, int n) {
    int wave = threadIdx.x >> 6, lane = threadIdx.x & 63;
    int row = blockIdx.x * 4 + wave;
    if (row >= n) return;
    int start = offs[row], d = degc[row];
    float a = 0.f, b = 0.f, c = 0.f, e = 0.f;
    int i = 0;
    for (; i + 4 <= d; i += 4) {
        int n0 = csr[start + i + 0];
        int n1 = csr[start + i + 1];
        int n2 = csr[start + i + 2];
        int n3 = csr[start + i + 3];
        a += H2[(size_t)n0 * 64 + lane];
        b += H2[(size_t)n1 * 64 + lane];
        c += H2[(size_t)n2 * 64 + lane];
        e += H2[(size_t)n3 * 64 + lane];
    }
    for (; i < d; ++i) {
        int n0 = csr[start + i];
        a += H2[(size_t)n0 * 64 + lane];
    }
    Out[(size_t)row * 64 + lane] = (a + b + c + e) * invdeg[row];
}

extern "C" void kernel_launch(void* const* d_in, const int* in_sizes, int n_in,
                              void* d_out, int out_size, void* d_ws, size_t ws_size,
                              hipStream_t stream) {
    const float* x    = (const float*)d_in[0];
    const float* W1   = (const float*)d_in[1];
    const float* W2   = (const float*)d_in[2];
    const int*   erow = (const int*)d_in[3];
    const int*   ecol = (const int*)d_in[4];
    const int N = in_sizes[0] / DIN;
    const int E = in_sizes[3];

    const int nb  = (N + (1 << BSH) - 1) >> BSH;   // 196 buckets (<=256)
    const int nch = (E + CHUNK - 1) / CHUNK;       // 196 chunks

    size_t o = 0;
    auto take = [&](size_t nbytes) {
        void* p = (char*)d_ws + o;
        o += (nbytes + 255) & ~(size_t)255;
        return p;
    };
    int*   HT     = (int*)take((size_t)nb * nch * 4);
    int*   bbase  = (int*)take((size_t)(nb + 1) * 4);
    int*   packed = (int*)take((size_t)E * 4);
    int*   csr    = (int*)take((size_t)E * 4);
    int*   offs   = (int*)take((size_t)N * 4);
    int*   degc   = (int*)take((size_t)N * 4);
    float* invdeg = (float*)take((size_t)N * 4);
    float* h1     = (float*)take((size_t)N * DH * 4);
    float* h      = (float*)take((size_t)N * DH * 4);
    float* h2     = h1;   // gemm2 output reuses h1 (dead after agg1)

    k_hist <<<nch, 256, 0, stream>>>(erow, HT, E, nb, nch);
    k_hscan<<<1,   256, 0, stream>>>(HT, bbase, nb, nch, E);
    k_part <<<nch, 256, 0, stream>>>(erow, ecol, HT, packed, E, nb, nch);
    k_build<<<nb,  256, 0, stream>>>(packed, bbase, csr, offs, degc, invdeg, N, nb);
    k_gemm1<<<(N + 63) / 64, 256, 0, stream>>>(x, W1, h1, N);
    k_agg1 <<<(N + 3) / 4, 256, 0, stream>>>(h1, offs, degc, invdeg, csr, h, N);
    k_gemm2<<<(N + 63) / 64, 256, 0, stream>>>(h, W2, h2, N);
    k_agg2 <<<(N + 3) / 4, 256, 0, stream>>>(h2, offs, degc, invdeg, csr, (float*)d_out, N);
}

// Round 7
// 452.729 us; speedup vs baseline: 4.4914x; 1.1138x over previous
//
#include <hip/hip_runtime.h>

// GraphSAGE 2-layer: logits = meanAgg(relu(meanAgg(x@W1)) @ W2)
// N=100000, E=1600000, D_IN=128, D_H=128, D_OUT=64, fp32 in/out.
//
// R2: 3-phase parallel scan. R3: agg x4 unroll; gemm float4 LDS reads.
// R4: FAILED - 1024-thr gemm -> VGPR cap 64 -> spills (4GB traffic).
// R5: gemm W from global (L2-hot), only X tile in LDS.
// R6: CSR build = 2-level counting sort, zero global atomics (scatter's
//     105MB random partial-line writes eliminated).
// R7: bf16 gather buffers. h1/h2 stored bf16 (RNE) by gemm epilogues;
//     agg gathers read bf16, accumulate fp32; unroll deepened 4->8 to
//     keep bytes-in-flight after halving per-neighbor transaction size.
//     Layer-1 output h stays fp32 (linear read by gemm2).

#define DIN 128
#define DH 128
#define DOUT 64

#define BSH 9                    // 512 rows per bucket
#define COLB 17                  // col fits 17 bits (N=100000 < 2^17)
#define COLM ((1 << COLB) - 1)
#define LRM ((1 << BSH) - 1)
#define CHUNK 8192               // edges per pass-1/3 block
#define CH_PT 32                 // edges per thread

__device__ __forceinline__ unsigned bfpack(float a, float b) {
    // two fp32 -> packed bf16x2 (round-to-nearest-even), a in low half
    unsigned ua = __float_as_uint(a);
    unsigned ub = __float_as_uint(b);
    ua += 0x7fffu + ((ua >> 16) & 1u);
    ub += 0x7fffu + ((ub >> 16) & 1u);
    return (ua >> 16) | (ub & 0xffff0000u);
}

// ---------------- CSR build (counting sort, R6) ----------------

__global__ __launch_bounds__(256) void k_hist(const int* __restrict__ row,
                                              int* __restrict__ HT,
                                              int E, int nb, int nch) {
    __shared__ int h[512];
    int t = threadIdx.x, c = blockIdx.x;
    for (int i = t; i < nb; i += 256) h[i] = 0;
    __syncthreads();
    int base = c * CHUNK;
#pragma unroll
    for (int i = 0; i < CH_PT; ++i) {
        int e = base + i * 256 + t;
        if (e < E) atomicAdd(&h[row[e] >> BSH], 1);
    }
    __syncthreads();
    for (int i = t; i < nb; i += 256) HT[(size_t)i * nch + c] = h[i];
}

__global__ __launch_bounds__(256) void k_hscan(int* __restrict__ HT,
                                               int* __restrict__ bucketBase,
                                               int nb, int nch, int E) {
    __shared__ int sh[256];
    int t = threadIdx.x;
    int run = 0;
    if (t < nb) {
        for (int c = 0; c < nch; ++c) {
            int v = HT[(size_t)t * nch + c];
            HT[(size_t)t * nch + c] = run;
            run += v;
        }
    }
    sh[t] = (t < nb) ? run : 0;
    __syncthreads();
    for (int d = 1; d < 256; d <<= 1) {
        int v = (t >= d) ? sh[t - d] : 0;
        __syncthreads();
        sh[t] += v;
        __syncthreads();
    }
    int base = (t == 0) ? 0 : sh[t - 1];
    if (t < nb) {
        bucketBase[t] = base;
        for (int c = 0; c < nch; ++c) HT[(size_t)t * nch + c] += base;
    }
    if (t == 0) bucketBase[nb] = E;
}

__global__ __launch_bounds__(256) void k_part(const int* __restrict__ row,
                                              const int* __restrict__ col,
                                              const int* __restrict__ HT,
                                              int* __restrict__ packed,
                                              int E, int nb, int nch) {
    __shared__ int cur[512];
    int t = threadIdx.x, c = blockIdx.x;
    for (int i = t; i < nb; i += 256) cur[i] = HT[(size_t)i * nch + c];
    __syncthreads();
    int base = c * CHUNK;
#pragma unroll
    for (int i = 0; i < CH_PT; ++i) {
        int e = base + i * 256 + t;
        if (e < E) {
            int r = row[e], cc = col[e];
            int b = r >> BSH;
            int pos = atomicAdd(&cur[b], 1);
            packed[pos] = ((r & LRM) << COLB) | cc;
        }
    }
}

__global__ __launch_bounds__(256) void k_build(const int* __restrict__ packed,
                                               const int* __restrict__ bucketBase,
                                               int* __restrict__ csr,
                                               int* __restrict__ offs,
                                               int* __restrict__ degc,
                                               float* __restrict__ invdeg,
                                               int N, int nb) {
    __shared__ int hist[512], scn[512], part[256];
    int t = threadIdx.x, b = blockIdx.x;
    int lo = bucketBase[b], hi = bucketBase[b + 1];
    int base_row = b << BSH;
    int nloc = N - base_row; if (nloc > 512) nloc = 512;
    hist[t] = 0; hist[t + 256] = 0;
    __syncthreads();
    for (int e = lo + t; e < hi; e += 256)
        atomicAdd(&hist[packed[e] >> COLB], 1);
    __syncthreads();
    int a = hist[2 * t], b2 = hist[2 * t + 1];
    part[t] = a + b2;
    __syncthreads();
    for (int d = 1; d < 256; d <<= 1) {
        int v = (t >= d) ? part[t - d] : 0;
        __syncthreads();
        part[t] += v;
        __syncthreads();
    }
    int bp = (t == 0) ? 0 : part[t - 1];
    scn[2 * t] = bp;
    scn[2 * t + 1] = bp + a;
    __syncthreads();
    for (int i = t; i < nloc; i += 256) {
        int r = base_row + i;
        offs[r] = lo + scn[i];
        int d = hist[i];
        degc[r] = d;
        invdeg[r] = 1.0f / (float)d;
    }
    __syncthreads();
    for (int e = lo + t; e < hi; e += 256) {
        int p = packed[e];
        int pos = lo + atomicAdd(&scn[p >> COLB], 1);
        csr[pos] = p & COLM;
    }
}

// ---------------- GEMMs ----------------

// h1b[n,128](bf16) = X[n,128] @ W[128,128]. 256 thr, 64x128 tile.
// Only X in LDS; W from global (L2-hot). Epilogue packs bf16x2.
__global__ __launch_bounds__(256) void k_gemm1(const float* __restrict__ X,
                                               const float* __restrict__ W,
                                               unsigned* __restrict__ H1b, int n) {
    __shared__ float xs[64][132];
    int tid = threadIdx.x;
    int r0 = blockIdx.x * 64;

    for (int i = tid; i < 64 * 32; i += 256) {
        int r = i >> 5, c4 = i & 31;
        float4 v = make_float4(0.f, 0.f, 0.f, 0.f);
        if (r0 + r < n) v = ((const float4*)X)[(size_t)(r0 + r) * 32 + c4];
        *(float4*)&xs[r][c4 * 4] = v;
    }
    __syncthreads();

    int cg = tid & 31;
    int rg = tid >> 5;
    float acc[8][4];
#pragma unroll
    for (int r = 0; r < 8; ++r)
#pragma unroll
        for (int c = 0; c < 4; ++c) acc[r][c] = 0.f;

    const float4* W4 = (const float4*)W;
#pragma unroll 2
    for (int k4 = 0; k4 < 32; ++k4) {
        float4 w0 = W4[(k4 * 4 + 0) * 32 + cg];
        float4 w1 = W4[(k4 * 4 + 1) * 32 + cg];
        float4 w2 = W4[(k4 * 4 + 2) * 32 + cg];
        float4 w3 = W4[(k4 * 4 + 3) * 32 + cg];
#pragma unroll
        for (int r = 0; r < 8; ++r) {
            float4 xv = *(const float4*)&xs[rg * 8 + r][k4 * 4];
            acc[r][0] += xv.x * w0.x + xv.y * w1.x + xv.z * w2.x + xv.w * w3.x;
            acc[r][1] += xv.x * w0.y + xv.y * w1.y + xv.z * w2.y + xv.w * w3.y;
            acc[r][2] += xv.x * w0.z + xv.y * w1.z + xv.z * w2.z + xv.w * w3.z;
            acc[r][3] += xv.x * w0.w + xv.y * w1.w + xv.z * w2.w + xv.w * w3.w;
        }
    }
#pragma unroll
    for (int r = 0; r < 8; ++r) {
        int rr = r0 + rg * 8 + r;
        if (rr < n) {
            uint2 p = make_uint2(bfpack(acc[r][0], acc[r][1]),
                                 bfpack(acc[r][2], acc[r][3]));
            *(uint2*)&H1b[(size_t)rr * 64 + cg * 2] = p;   // 64 uints/row
        }
    }
}

// h2b[n,64](bf16) = H[n,128] @ W[128,64]. 256 thr, 64x64 tile.
__global__ __launch_bounds__(256) void k_gemm2(const float* __restrict__ X,
                                               const float* __restrict__ W,
                                               unsigned* __restrict__ H2b, int n) {
    __shared__ float xs[64][132];
    int tid = threadIdx.x;
    int r0 = blockIdx.x * 64;

    for (int i = tid; i < 64 * 32; i += 256) {
        int r = i >> 5, c4 = i & 31;
        float4 v = make_float4(0.f, 0.f, 0.f, 0.f);
        if (r0 + r < n) v = ((const float4*)X)[(size_t)(r0 + r) * 32 + c4];
        *(float4*)&xs[r][c4 * 4] = v;
    }
    __syncthreads();

    int cg = tid & 15;
    int rg = tid >> 4;
    float acc[4][4];
#pragma unroll
    for (int r = 0; r < 4; ++r)
#pragma unroll
        for (int c = 0; c < 4; ++c) acc[r][c] = 0.f;

    const float4* W4 = (const float4*)W;
#pragma unroll 2
    for (int k4 = 0; k4 < 32; ++k4) {
        float4 w0 = W4[(k4 * 4 + 0) * 16 + cg];
        float4 w1 = W4[(k4 * 4 + 1) * 16 + cg];
        float4 w2 = W4[(k4 * 4 + 2) * 16 + cg];
        float4 w3 = W4[(k4 * 4 + 3) * 16 + cg];
#pragma unroll
        for (int r = 0; r < 4; ++r) {
            float4 xv = *(const float4*)&xs[rg * 4 + r][k4 * 4];
            acc[r][0] += xv.x * w0.x + xv.y * w1.x + xv.z * w2.x + xv.w * w3.x;
            acc[r][1] += xv.x * w0.y + xv.y * w1.y + xv.z * w2.y + xv.w * w3.y;
            acc[r][2] += xv.x * w0.z + xv.y * w1.z + xv.z * w2.z + xv.w * w3.z;
            acc[r][3] += xv.x * w0.w + xv.y * w1.w + xv.z * w2.w + xv.w * w3.w;
        }
    }
#pragma unroll
    for (int r = 0; r < 4; ++r) {
        int rr = r0 + rg * 4 + r;
        if (rr < n) {
            uint2 p = make_uint2(bfpack(acc[r][0], acc[r][1]),
                                 bfpack(acc[r][2], acc[r][3]));
            *(uint2*)&H2b[(size_t)rr * 32 + cg * 2] = p;   // 32 uints/row
        }
    }
}

// ---------------- Aggregations ----------------

// agg1: h[row] = relu( (1/deg) * sum_{c} h1b[c] ), D=128 bf16 in, fp32 out.
// One wave/row; lane loads bf16x2 (uint). Unroll x8, 16 fp32 chains.
__global__ __launch_bounds__(256) void k_agg1(const unsigned* __restrict__ H1b,
                                              const int* __restrict__ offs,
                                              const int* __restrict__ degc,
                                              const float* __restrict__ invdeg,
                                              const int* __restrict__ csr,
                                              float* __restrict__ Hout, int n) {
    int wave = threadIdx.x >> 6, lane = threadIdx.x & 63;
    int row = blockIdx.x * 4 + wave;
    if (row >= n) return;
    int start = offs[row], d = degc[row];
    float s0[8], s1[8];
#pragma unroll
    for (int j = 0; j < 8; ++j) { s0[j] = 0.f; s1[j] = 0.f; }
    int i = 0;
    for (; i + 8 <= d; i += 8) {
        int idx[8];
#pragma unroll
        for (int j = 0; j < 8; ++j) idx[j] = csr[start + i + j];
        unsigned v[8];
#pragma unroll
        for (int j = 0; j < 8; ++j) v[j] = H1b[(size_t)idx[j] * 64 + lane];
#pragma unroll
        for (int j = 0; j < 8; ++j) {
            s0[j] += __uint_as_float(v[j] << 16);
            s1[j] += __uint_as_float(v[j] & 0xffff0000u);
        }
    }
    for (; i < d; ++i) {
        int c = csr[start + i];
        unsigned v = H1b[(size_t)c * 64 + lane];
        s0[0] += __uint_as_float(v << 16);
        s1[0] += __uint_as_float(v & 0xffff0000u);
    }
    float t0 = (s0[0] + s0[1]) + (s0[2] + s0[3]) + ((s0[4] + s0[5]) + (s0[6] + s0[7]));
    float t1 = (s1[0] + s1[1]) + (s1[2] + s1[3]) + ((s1[4] + s1[5]) + (s1[6] + s1[7]));
    float inv = invdeg[row];
    t0 = fmaxf(t0 * inv, 0.f);
    t1 = fmaxf(t1 * inv, 0.f);
    *(float2*)&Hout[(size_t)row * 128 + lane * 2] = make_float2(t0, t1);
}

// agg2: Out[row] = (1/deg) * sum h2b[c], D=64 bf16 in, fp32 out.
// One wave/row; lane loads one bf16 (ushort). Unroll x8.
__global__ __launch_bounds__(256) void k_agg2(const unsigned short* __restrict__ H2b,
                                              const int* __restrict__ offs,
                                              const int* __restrict__ degc,
                                              const float* __restrict__ invdeg,
                                              const int* __restrict__ csr,
                                              float* __restrict__ Out, int n) {
    int wave = threadIdx.x >> 6, lane = threadIdx.x & 63;
    int row = blockIdx.x * 4 + wave;
    if (row >= n) return;
    int start = offs[row], d = degc[row];
    float s[8];
#pragma unroll
    for (int j = 0; j < 8; ++j) s[j] = 0.f;
    int i = 0;
    for (; i + 8 <= d; i += 8) {
        int idx[8];
#pragma unroll
        for (int j = 0; j < 8; ++j) idx[j] = csr[start + i + j];
        unsigned short v[8];
#pragma unroll
        for (int j = 0; j < 8; ++j) v[j] = H2b[(size_t)idx[j] * 64 + lane];
#pragma unroll
        for (int j = 0; j < 8; ++j)
            s[j] += __uint_as_float(((unsigned)v[j]) << 16);
    }
    for (; i < d; ++i) {
        int c = csr[start + i];
        s[0] += __uint_as_float(((unsigned)H2b[(size_t)c * 64 + lane]) << 16);
    }
    float t = (s[0] + s[1]) + (s[2] + s[3]) + ((s[4] + s[5]) + (s[6] + s[7]));
    Out[(size_t)row * 64 + lane] = t * invdeg[row];
}

extern "C" void kernel_launch(void* const* d_in, const int* in_sizes, int n_in,
                              void* d_out, int out_size, void* d_ws, size_t ws_size,
                              hipStream_t stream) {
    const float* x    = (const float*)d_in[0];
    const float* W1   = (const float*)d_in[1];
    const float* W2   = (const float*)d_in[2];
    const int*   erow = (const int*)d_in[3];
    const int*   ecol = (const int*)d_in[4];
    const int N = in_sizes[0] / DIN;
    const int E = in_sizes[3];

    const int nb  = (N + (1 << BSH) - 1) >> BSH;   // 196 buckets (<=256)
    const int nch = (E + CHUNK - 1) / CHUNK;       // 196 chunks

    size_t o = 0;
    auto take = [&](size_t nbytes) {
        void* p = (char*)d_ws + o;
        o += (nbytes + 255) & ~(size_t)255;
        return p;
    };
    int*      HT     = (int*)take((size_t)nb * nch * 4);
    int*      bbase  = (int*)take((size_t)(nb + 1) * 4);
    int*      packed = (int*)take((size_t)E * 4);
    int*      csr    = (int*)take((size_t)E * 4);
    int*      offs   = (int*)take((size_t)N * 4);
    int*      degc   = (int*)take((size_t)N * 4);
    float*    invdeg = (float*)take((size_t)N * 4);
    unsigned* h1b    = (unsigned*)take((size_t)N * DH * 2);    // bf16
    float*    h      = (float*)take((size_t)N * DH * 4);       // fp32
    unsigned* h2b    = h1b;   // bf16, reuses h1b (dead after agg1)

    k_hist <<<nch, 256, 0, stream>>>(erow, HT, E, nb, nch);
    k_hscan<<<1,   256, 0, stream>>>(HT, bbase, nb, nch, E);
    k_part <<<nch, 256, 0, stream>>>(erow, ecol, HT, packed, E, nb, nch);
    k_build<<<nb,  256, 0, stream>>>(packed, bbase, csr, offs, degc, invdeg, N, nb);
    k_gemm1<<<(N + 63) / 64, 256, 0, stream>>>(x, W1, h1b, N);
    k_agg1 <<<(N + 3) / 4, 256, 0, stream>>>(h1b, offs, degc, invdeg, csr, h, N);
    k_gemm2<<<(N + 63) / 64, 256, 0, stream>>>(h, W2, h2b, N);
    k_agg2 <<<(N + 3) / 4, 256, 0, stream>>>((const unsigned short*)h2b, offs, degc,
                                             invdeg, csr, (float*)d_out, N);
}

// Round 8
// 384.978 us; speedup vs baseline: 5.2818x; 1.1760x over previous
//
#include <hip/hip_runtime.h>

// GraphSAGE 2-layer: logits = meanAgg(relu(meanAgg(x@W1)) @ W2)
// N=100000, E=1600000, D_IN=128, D_H=128, D_OUT=64, fp32 in/out.
//
// R2: 3-phase parallel scan. R3: agg x4 unroll; gemm float4 LDS reads.
// R4: FAILED - 1024-thr gemm -> VGPR cap 64 -> spills (4GB traffic).
// R5: gemm W from global (L2-hot), only X tile in LDS.
// R6: CSR build = 2-level counting sort, zero global atomics.
// R7: bf16 gather buffers (h1/h2 bf16 RNE; agg accumulates fp32); x8 unroll.
// R8: k_hscan (81us, single block serially walking 196x196 HT) split into
//     k_hscan_row (nb blocks, LDS scan per bucket row) + k_hscan_base
//     (1 tiny block over bucket totals); k_part adds bbase[b] at cursor load.

#define DIN 128
#define DH 128
#define DOUT 64

#define BSH 9                    // 512 rows per bucket
#define COLB 17                  // col fits 17 bits (N=100000 < 2^17)
#define COLM ((1 << COLB) - 1)
#define LRM ((1 << BSH) - 1)
#define CHUNK 8192               // edges per pass-1/3 block
#define CH_PT 32                 // edges per thread

__device__ __forceinline__ unsigned bfpack(float a, float b) {
    unsigned ua = __float_as_uint(a);
    unsigned ub = __float_as_uint(b);
    ua += 0x7fffu + ((ua >> 16) & 1u);
    ub += 0x7fffu + ((ub >> 16) & 1u);
    return (ua >> 16) | (ub & 0xffff0000u);
}

// ---------------- CSR build (counting sort) ----------------

__global__ __launch_bounds__(256) void k_hist(const int* __restrict__ row,
                                              int* __restrict__ HT,
                                              int E, int nb, int nch) {
    __shared__ int h[512];
    int t = threadIdx.x, c = blockIdx.x;
    for (int i = t; i < nb; i += 256) h[i] = 0;
    __syncthreads();
    int base = c * CHUNK;
#pragma unroll
    for (int i = 0; i < CH_PT; ++i) {
        int e = base + i * 256 + t;
        if (e < E) atomicAdd(&h[row[e] >> BSH], 1);
    }
    __syncthreads();
    for (int i = t; i < nb; i += 256) HT[(size_t)i * nch + c] = h[i];
}

// Per-bucket row scan: block b exclusive-scans HT[b][0..nch) in place
// (bucket-local offsets), writes bucket total to bsum[b].
__global__ __launch_bounds__(256) void k_hscan_row(int* __restrict__ HT,
                                                   int* __restrict__ bsum,
                                                   int nch) {
    __shared__ int sh[256];
    int b = blockIdx.x, t = threadIdx.x;
    int carry = 0;
    for (int tile = 0; tile < nch; tile += 256) {
        int idx = tile + t;
        int v = (idx < nch) ? HT[(size_t)b * nch + idx] : 0;
        sh[t] = v;
        __syncthreads();
        for (int d = 1; d < 256; d <<= 1) {
            int u = (t >= d) ? sh[t - d] : 0;
            __syncthreads();
            sh[t] += u;
            __syncthreads();
        }
        if (idx < nch) HT[(size_t)b * nch + idx] = carry + sh[t] - v;
        carry += sh[255];
        __syncthreads();
    }
    if (t == 0) bsum[b] = carry;
}

// Exclusive scan of bucket totals -> bucketBase (nb <= 256).
__global__ __launch_bounds__(256) void k_hscan_base(const int* __restrict__ bsum,
                                                    int* __restrict__ bucketBase,
                                                    int nb, int E) {
    __shared__ int sh[256];
    int t = threadIdx.x;
    int v = (t < nb) ? bsum[t] : 0;
    sh[t] = v;
    __syncthreads();
    for (int d = 1; d < 256; d <<= 1) {
        int u = (t >= d) ? sh[t - d] : 0;
        __syncthreads();
        sh[t] += u;
        __syncthreads();
    }
    if (t < nb) bucketBase[t] = sh[t] - v;
    if (t == 0) bucketBase[nb] = E;
}

// Chunk c scatters edges into per-(chunk,bucket) runs; cursor = bucket-local
// HT entry + bucket base.
__global__ __launch_bounds__(256) void k_part(const int* __restrict__ row,
                                              const int* __restrict__ col,
                                              const int* __restrict__ HT,
                                              const int* __restrict__ bucketBase,
                                              int* __restrict__ packed,
                                              int E, int nb, int nch) {
    __shared__ int cur[512];
    int t = threadIdx.x, c = blockIdx.x;
    for (int i = t; i < nb; i += 256)
        cur[i] = HT[(size_t)i * nch + c] + bucketBase[i];
    __syncthreads();
    int base = c * CHUNK;
#pragma unroll
    for (int i = 0; i < CH_PT; ++i) {
        int e = base + i * 256 + t;
        if (e < E) {
            int r = row[e], cc = col[e];
            int b = r >> BSH;
            int pos = atomicAdd(&cur[b], 1);
            packed[pos] = ((r & LRM) << COLB) | cc;
        }
    }
}

__global__ __launch_bounds__(256) void k_build(const int* __restrict__ packed,
                                               const int* __restrict__ bucketBase,
                                               int* __restrict__ csr,
                                               int* __restrict__ offs,
                                               int* __restrict__ degc,
                                               float* __restrict__ invdeg,
                                               int N, int nb) {
    __shared__ int hist[512], scn[512], part[256];
    int t = threadIdx.x, b = blockIdx.x;
    int lo = bucketBase[b], hi = bucketBase[b + 1];
    int base_row = b << BSH;
    int nloc = N - base_row; if (nloc > 512) nloc = 512;
    hist[t] = 0; hist[t + 256] = 0;
    __syncthreads();
    for (int e = lo + t; e < hi; e += 256)
        atomicAdd(&hist[packed[e] >> COLB], 1);
    __syncthreads();
    int a = hist[2 * t], b2 = hist[2 * t + 1];
    part[t] = a + b2;
    __syncthreads();
    for (int d = 1; d < 256; d <<= 1) {
        int v = (t >= d) ? part[t - d] : 0;
        __syncthreads();
        part[t] += v;
        __syncthreads();
    }
    int bp = (t == 0) ? 0 : part[t - 1];
    scn[2 * t] = bp;
    scn[2 * t + 1] = bp + a;
    __syncthreads();
    for (int i = t; i < nloc; i += 256) {
        int r = base_row + i;
        offs[r] = lo + scn[i];
        int d = hist[i];
        degc[r] = d;
        invdeg[r] = 1.0f / (float)d;
    }
    __syncthreads();
    for (int e = lo + t; e < hi; e += 256) {
        int p = packed[e];
        int pos = lo + atomicAdd(&scn[p >> COLB], 1);
        csr[pos] = p & COLM;
    }
}

// ---------------- GEMMs ----------------

__global__ __launch_bounds__(256) void k_gemm1(const float* __restrict__ X,
                                               const float* __restrict__ W,
                                               unsigned* __restrict__ H1b, int n) {
    __shared__ float xs[64][132];
    int tid = threadIdx.x;
    int r0 = blockIdx.x * 64;

    for (int i = tid; i < 64 * 32; i += 256) {
        int r = i >> 5, c4 = i & 31;
        float4 v = make_float4(0.f, 0.f, 0.f, 0.f);
        if (r0 + r < n) v = ((const float4*)X)[(size_t)(r0 + r) * 32 + c4];
        *(float4*)&xs[r][c4 * 4] = v;
    }
    __syncthreads();

    int cg = tid & 31;
    int rg = tid >> 5;
    float acc[8][4];
#pragma unroll
    for (int r = 0; r < 8; ++r)
#pragma unroll
        for (int c = 0; c < 4; ++c) acc[r][c] = 0.f;

    const float4* W4 = (const float4*)W;
#pragma unroll 2
    for (int k4 = 0; k4 < 32; ++k4) {
        float4 w0 = W4[(k4 * 4 + 0) * 32 + cg];
        float4 w1 = W4[(k4 * 4 + 1) * 32 + cg];
        float4 w2 = W4[(k4 * 4 + 2) * 32 + cg];
        float4 w3 = W4[(k4 * 4 + 3) * 32 + cg];
#pragma unroll
        for (int r = 0; r < 8; ++r) {
            float4 xv = *(const float4*)&xs[rg * 8 + r][k4 * 4];
            acc[r][0] += xv.x * w0.x + xv.y * w1.x + xv.z * w2.x + xv.w * w3.x;
            acc[r][1] += xv.x * w0.y + xv.y * w1.y + xv.z * w2.y + xv.w * w3.y;
            acc[r][2] += xv.x * w0.z + xv.y * w1.z + xv.z * w2.z + xv.w * w3.z;
            acc[r][3] += xv.x * w0.w + xv.y * w1.w + xv.z * w2.w + xv.w * w3.w;
        }
    }
#pragma unroll
    for (int r = 0; r < 8; ++r) {
        int rr = r0 + rg * 8 + r;
        if (rr < n) {
            uint2 p = make_uint2(bfpack(acc[r][0], acc[r][1]),
                                 bfpack(acc[r][2], acc[r][3]));
            *(uint2*)&H1b[(size_t)rr * 64 + cg * 2] = p;
        }
    }
}

__global__ __launch_bounds__(256) void k_gemm2(const float* __restrict__ X,
                                               const float* __restrict__ W,
                                               unsigned* __restrict__ H2b, int n) {
    __shared__ float xs[64][132];
    int tid = threadIdx.x;
    int r0 = blockIdx.x * 64;

    for (int i = tid; i < 64 * 32; i += 256) {
        int r = i >> 5, c4 = i & 31;
        float4 v = make_float4(0.f, 0.f, 0.f, 0.f);
        if (r0 + r < n) v = ((const float4*)X)[(size_t)(r0 + r) * 32 + c4];
        *(float4*)&xs[r][c4 * 4] = v;
    }
    __syncthreads();

    int cg = tid & 15;
    int rg = tid >> 4;
    float acc[4][4];
#pragma unroll
    for (int r = 0; r < 4; ++r)
#pragma unroll
        for (int c = 0; c < 4; ++c) acc[r][c] = 0.f;

    const float4* W4 = (const float4*)W;
#pragma unroll 2
    for (int k4 = 0; k4 < 32; ++k4) {
        float4 w0 = W4[(k4 * 4 + 0) * 16 + cg];
        float4 w1 = W4[(k4 * 4 + 1) * 16 + cg];
        float4 w2 = W4[(k4 * 4 + 2) * 16 + cg];
        float4 w3 = W4[(k4 * 4 + 3) * 16 + cg];
#pragma unroll
        for (int r = 0; r < 4; ++r) {
            float4 xv = *(const float4*)&xs[rg * 4 + r][k4 * 4];
            acc[r][0] += xv.x * w0.x + xv.y * w1.x + xv.z * w2.x + xv.w * w3.x;
            acc[r][1] += xv.x * w0.y + xv.y * w1.y + xv.z * w2.y + xv.w * w3.y;
            acc[r][2] += xv.x * w0.z + xv.y * w1.z + xv.z * w2.z + xv.w * w3.z;
            acc[r][3] += xv.x * w0.w + xv.y * w1.w + xv.z * w2.w + xv.w * w3.w;
        }
    }
#pragma unroll
    for (int r = 0; r < 4; ++r) {
        int rr = r0 + rg * 4 + r;
        if (rr < n) {
            uint2 p = make_uint2(bfpack(acc[r][0], acc[r][1]),
                                 bfpack(acc[r][2], acc[r][3]));
            *(uint2*)&H2b[(size_t)rr * 32 + cg * 2] = p;
        }
    }
}

// ---------------- Aggregations ----------------

__global__ __launch_bounds__(256) void k_agg1(const unsigned* __restrict__ H1b,
                                              const int* __restrict__ offs,
                                              const int* __restrict__ degc,
                                              const float* __restrict__ invdeg,
                                              const int* __restrict__ csr,
                                              float* __restrict__ Hout, int n) {
    int wave = threadIdx.x >> 6, lane = threadIdx.x & 63;
    int row = blockIdx.x * 4 + wave;
    if (row >= n) return;
    int start = offs[row], d = degc[row];
    float s0[8], s1[8];
#pragma unroll
    for (int j = 0; j < 8; ++j) { s0[j] = 0.f; s1[j] = 0.f; }
    int i = 0;
    for (; i + 8 <= d; i += 8) {
        int idx[8];
#pragma unroll
        for (int j = 0; j < 8; ++j) idx[j] = csr[start + i + j];
        unsigned v[8];
#pragma unroll
        for (int j = 0; j < 8; ++j) v[j] = H1b[(size_t)idx[j] * 64 + lane];
#pragma unroll
        for (int j = 0; j < 8; ++j) {
            s0[j] += __uint_as_float(v[j] << 16);
            s1[j] += __uint_as_float(v[j] & 0xffff0000u);
        }
    }
    for (; i < d; ++i) {
        int c = csr[start + i];
        unsigned v = H1b[(size_t)c * 64 + lane];
        s0[0] += __uint_as_float(v << 16);
        s1[0] += __uint_as_float(v & 0xffff0000u);
    }
    float t0 = (s0[0] + s0[1]) + (s0[2] + s0[3]) + ((s0[4] + s0[5]) + (s0[6] + s0[7]));
    float t1 = (s1[0] + s1[1]) + (s1[2] + s1[3]) + ((s1[4] + s1[5]) + (s1[6] + s1[7]));
    float inv = invdeg[row];
    t0 = fmaxf(t0 * inv, 0.f);
    t1 = fmaxf(t1 * inv, 0.f);
    *(float2*)&Hout[(size_t)row * 128 + lane * 2] = make_float2(t0, t1);
}

__global__ __launch_bounds__(256) void k_agg2(const unsigned short* __restrict__ H2b,
                                              const int* __restrict__ offs,
                                              const int* __restrict__ degc,
                                              const float* __restrict__ invdeg,
                                              const int* __restrict__ csr,
                                              float* __restrict__ Out, int n) {
    int wave = threadIdx.x >> 6, lane = threadIdx.x & 63;
    int row = blockIdx.x * 4 + wave;
    if (row >= n) return;
    int start = offs[row], d = degc[row];
    float s[8];
#pragma unroll
    for (int j = 0; j < 8; ++j) s[j] = 0.f;
    int i = 0;
    for (; i + 8 <= d; i += 8) {
        int idx[8];
#pragma unroll
        for (int j = 0; j < 8; ++j) idx[j] = csr[start + i + j];
        unsigned short v[8];
#pragma unroll
        for (int j = 0; j < 8; ++j) v[j] = H2b[(size_t)idx[j] * 64 + lane];
#pragma unroll
        for (int j = 0; j < 8; ++j)
            s[j] += __uint_as_float(((unsigned)v[j]) << 16);
    }
    for (; i < d; ++i) {
        int c = csr[start + i];
        s[0] += __uint_as_float(((unsigned)H2b[(size_t)c * 64 + lane]) << 16);
    }
    float t = (s[0] + s[1]) + (s[2] + s[3]) + ((s[4] + s[5]) + (s[6] + s[7]));
    Out[(size_t)row * 64 + lane] = t * invdeg[row];
}

extern "C" void kernel_launch(void* const* d_in, const int* in_sizes, int n_in,
                              void* d_out, int out_size, void* d_ws, size_t ws_size,
                              hipStream_t stream) {
    const float* x    = (const float*)d_in[0];
    const float* W1   = (const float*)d_in[1];
    const float* W2   = (const float*)d_in[2];
    const int*   erow = (const int*)d_in[3];
    const int*   ecol = (const int*)d_in[4];
    const int N = in_sizes[0] / DIN;
    const int E = in_sizes[3];

    const int nb  = (N + (1 << BSH) - 1) >> BSH;   // 196 buckets (<=256)
    const int nch = (E + CHUNK - 1) / CHUNK;       // 196 chunks

    size_t o = 0;
    auto take = [&](size_t nbytes) {
        void* p = (char*)d_ws + o;
        o += (nbytes + 255) & ~(size_t)255;
        return p;
    };
    int*      HT     = (int*)take((size_t)nb * nch * 4);
    int*      bsum   = (int*)take((size_t)nb * 4);
    int*      bbase  = (int*)take((size_t)(nb + 1) * 4);
    int*      packed = (int*)take((size_t)E * 4);
    int*      csr    = (int*)take((size_t)E * 4);
    int*      offs   = (int*)take((size_t)N * 4);
    int*      degc   = (int*)take((size_t)N * 4);
    float*    invdeg = (float*)take((size_t)N * 4);
    unsigned* h1b    = (unsigned*)take((size_t)N * DH * 2);    // bf16
    float*    h      = (float*)take((size_t)N * DH * 4);       // fp32
    unsigned* h2b    = h1b;   // bf16, reuses h1b (dead after agg1)

    k_hist      <<<nch, 256, 0, stream>>>(erow, HT, E, nb, nch);
    k_hscan_row <<<nb,  256, 0, stream>>>(HT, bsum, nch);
    k_hscan_base<<<1,   256, 0, stream>>>(bsum, bbase, nb, E);
    k_part      <<<nch, 256, 0, stream>>>(erow, ecol, HT, bbase, packed, E, nb, nch);
    k_build     <<<nb,  256, 0, stream>>>(packed, bbase, csr, offs, degc, invdeg, N, nb);
    k_gemm1<<<(N + 63) / 64, 256, 0, stream>>>(x, W1, h1b, N);
    k_agg1 <<<(N + 3) / 4, 256, 0, stream>>>(h1b, offs, degc, invdeg, csr, h, N);
    k_gemm2<<<(N + 63) / 64, 256, 0, stream>>>(h, W2, h2b, N);
    k_agg2 <<<(N + 3) / 4, 256, 0, stream>>>((const unsigned short*)h2b, offs, degc,
                                             invdeg, csr, (float*)d_out, N);
}

// Round 9
// 312.341 us; speedup vs baseline: 6.5101x; 1.2326x over previous
//
#include <hip/hip_runtime.h>

// GraphSAGE 2-layer: logits = meanAgg(relu(meanAgg(x@W1)) @ W2)
// N=100000, E=1600000, D_IN=128, D_H=128, D_OUT=64, fp32 in/out.
//
// R2: parallel scan. R3: agg x4 unroll. R4: FAILED 1024-thr gemm (spills).
// R5: gemm W from global. R6: counting-sort CSR build (no global atomics).
// R7: bf16 gather buffers, x8 unroll. R8: parallel HT scan.
// R9: MFMA gemms (mfma_f32_16x16x32_bf16; A=X rows m=lane&15, B=W^T rows
//     n=lane&15 k-fast, D col=lane&15 row=quad*4+reg). k_prep transposes
//     W1/W2 to bf16 [n][k] once. agg1 emits h in bf16 (gemm2 MFMA input,
//     halves agg1 write). CHUNK 8192->4096 (2x hist/part blocks).

#define DIN 128
#define DH 128
#define DOUT 64

#define BSH 9                    // 512 rows per bucket
#define COLB 17                  // col fits 17 bits (N=100000 < 2^17)
#define COLM ((1 << COLB) - 1)
#define LRM ((1 << BSH) - 1)
#define CHUNK 4096               // edges per hist/part block
#define CH_PT 16                 // edges per thread

typedef __attribute__((ext_vector_type(8))) short short8;
typedef __attribute__((ext_vector_type(4))) float floatx4;

__device__ __forceinline__ unsigned bfpack(float a, float b) {
    unsigned ua = __float_as_uint(a);
    unsigned ub = __float_as_uint(b);
    ua += 0x7fffu + ((ua >> 16) & 1u);
    ub += 0x7fffu + ((ub >> 16) & 1u);
    return (ua >> 16) | (ub & 0xffff0000u);
}
__device__ __forceinline__ unsigned short bf1(float a) {
    unsigned u = __float_as_uint(a);
    u += 0x7fffu + ((u >> 16) & 1u);
    return (unsigned short)(u >> 16);
}

// ---------------- weight prep: fp32 [k][n] -> bf16 [n][k] ----------------
__global__ __launch_bounds__(256) void k_prep(const float* __restrict__ W1,
                                              const float* __restrict__ W2,
                                              unsigned short* __restrict__ Wt1,
                                              unsigned short* __restrict__ Wt2) {
    int idx = blockIdx.x * 256 + threadIdx.x;
    if (idx < 128 * 128) {
        int k = idx >> 7, nn = idx & 127;
        Wt1[nn * 128 + k] = bf1(W1[idx]);
    }
    int i2 = idx - 128 * 128;
    if (i2 >= 0 && i2 < 128 * 64) {
        int k = i2 >> 6, nn = i2 & 63;
        Wt2[nn * 128 + k] = bf1(W2[i2]);
    }
}

// ---------------- CSR build (counting sort) ----------------

__global__ __launch_bounds__(256) void k_hist(const int* __restrict__ row,
                                              int* __restrict__ HT,
                                              int E, int nb, int nch) {
    __shared__ int h[512];
    int t = threadIdx.x, c = blockIdx.x;
    for (int i = t; i < nb; i += 256) h[i] = 0;
    __syncthreads();
    int base = c * CHUNK;
#pragma unroll
    for (int i = 0; i < CH_PT; ++i) {
        int e = base + i * 256 + t;
        if (e < E) atomicAdd(&h[row[e] >> BSH], 1);
    }
    __syncthreads();
    for (int i = t; i < nb; i += 256) HT[(size_t)i * nch + c] = h[i];
}

__global__ __launch_bounds__(256) void k_hscan_row(int* __restrict__ HT,
                                                   int* __restrict__ bsum,
                                                   int nch) {
    __shared__ int sh[256];
    int b = blockIdx.x, t = threadIdx.x;
    int carry = 0;
    for (int tile = 0; tile < nch; tile += 256) {
        int idx = tile + t;
        int v = (idx < nch) ? HT[(size_t)b * nch + idx] : 0;
        sh[t] = v;
        __syncthreads();
        for (int d = 1; d < 256; d <<= 1) {
            int u = (t >= d) ? sh[t - d] : 0;
            __syncthreads();
            sh[t] += u;
            __syncthreads();
        }
        if (idx < nch) HT[(size_t)b * nch + idx] = carry + sh[t] - v;
        carry += sh[255];
        __syncthreads();
    }
    if (t == 0) bsum[b] = carry;
}

__global__ __launch_bounds__(256) void k_hscan_base(const int* __restrict__ bsum,
                                                    int* __restrict__ bucketBase,
                                                    int nb, int E) {
    __shared__ int sh[256];
    int t = threadIdx.x;
    int v = (t < nb) ? bsum[t] : 0;
    sh[t] = v;
    __syncthreads();
    for (int d = 1; d < 256; d <<= 1) {
        int u = (t >= d) ? sh[t - d] : 0;
        __syncthreads();
        sh[t] += u;
        __syncthreads();
    }
    if (t < nb) bucketBase[t] = sh[t] - v;
    if (t == 0) bucketBase[nb] = E;
}

__global__ __launch_bounds__(256) void k_part(const int* __restrict__ row,
                                              const int* __restrict__ col,
                                              const int* __restrict__ HT,
                                              const int* __restrict__ bucketBase,
                                              int* __restrict__ packed,
                                              int E, int nb, int nch) {
    __shared__ int cur[512];
    int t = threadIdx.x, c = blockIdx.x;
    for (int i = t; i < nb; i += 256)
        cur[i] = HT[(size_t)i * nch + c] + bucketBase[i];
    __syncthreads();
    int base = c * CHUNK;
#pragma unroll
    for (int i = 0; i < CH_PT; ++i) {
        int e = base + i * 256 + t;
        if (e < E) {
            int r = row[e], cc = col[e];
            int b = r >> BSH;
            int pos = atomicAdd(&cur[b], 1);
            packed[pos] = ((r & LRM) << COLB) | cc;
        }
    }
}

__global__ __launch_bounds__(256) void k_build(const int* __restrict__ packed,
                                               const int* __restrict__ bucketBase,
                                               int* __restrict__ csr,
                                               int* __restrict__ offs,
                                               int* __restrict__ degc,
                                               float* __restrict__ invdeg,
                                               int N, int nb) {
    __shared__ int hist[512], scn[512], part[256];
    int t = threadIdx.x, b = blockIdx.x;
    int lo = bucketBase[b], hi = bucketBase[b + 1];
    int base_row = b << BSH;
    int nloc = N - base_row; if (nloc > 512) nloc = 512;
    hist[t] = 0; hist[t + 256] = 0;
    __syncthreads();
    for (int e = lo + t; e < hi; e += 256)
        atomicAdd(&hist[packed[e] >> COLB], 1);
    __syncthreads();
    int a = hist[2 * t], b2 = hist[2 * t + 1];
    part[t] = a + b2;
    __syncthreads();
    for (int d = 1; d < 256; d <<= 1) {
        int v = (t >= d) ? part[t - d] : 0;
        __syncthreads();
        part[t] += v;
        __syncthreads();
    }
    int bp = (t == 0) ? 0 : part[t - 1];
    scn[2 * t] = bp;
    scn[2 * t + 1] = bp + a;
    __syncthreads();
    for (int i = t; i < nloc; i += 256) {
        int r = base_row + i;
        offs[r] = lo + scn[i];
        int d = hist[i];
        degc[r] = d;
        invdeg[r] = 1.0f / (float)d;
    }
    __syncthreads();
    for (int e = lo + t; e < hi; e += 256) {
        int p = packed[e];
        int pos = lo + atomicAdd(&scn[p >> COLB], 1);
        csr[pos] = p & COLM;
    }
}

// ---------------- MFMA GEMMs ----------------

// h1b[n,128](bf16) = X @ W1. 256 thr, 64-row block; wave w: rows w*16..+15.
// xs: X tile cast to bf16; wt: W1^T (bf16 [n][k]) staged from Wt1.
__global__ __launch_bounds__(256) void k_gemm1(const float* __restrict__ X,
                                               const unsigned short* __restrict__ Wt,
                                               unsigned short* __restrict__ H1b, int n) {
    __shared__ unsigned short xs[64][136];    // pitch 272B: 2-way-bank-safe b128
    __shared__ unsigned short wt[128][136];
    int tid = threadIdx.x;
    int r0 = blockIdx.x * 64;

    for (int i = tid; i < 64 * 32; i += 256) {
        int r = i >> 5, c4 = i & 31;
        float4 v = make_float4(0.f, 0.f, 0.f, 0.f);
        if (r0 + r < n) v = ((const float4*)X)[(size_t)(r0 + r) * 32 + c4];
        *(uint2*)&xs[r][c4 * 4] = make_uint2(bfpack(v.x, v.y), bfpack(v.z, v.w));
    }
    for (int i = tid; i < 128 * 16; i += 256) {
        int r = i >> 4, c = i & 15;
        *(uint4*)&wt[r][c * 8] = ((const uint4*)Wt)[r * 16 + c];
    }
    __syncthreads();

    int w = tid >> 6, lane = tid & 63;
    int ml = lane & 15, q = lane >> 4;
    floatx4 acc[8];
#pragma unroll
    for (int t = 0; t < 8; ++t) acc[t] = (floatx4)(0.f);

#pragma unroll
    for (int kc = 0; kc < 4; ++kc) {
        short8 af = *(const short8*)&xs[w * 16 + ml][kc * 32 + q * 8];
#pragma unroll
        for (int nt = 0; nt < 8; ++nt) {
            short8 bf = *(const short8*)&wt[nt * 16 + ml][kc * 32 + q * 8];
            acc[nt] = __builtin_amdgcn_mfma_f32_16x16x32_bf16(af, bf, acc[nt], 0, 0, 0);
        }
    }
#pragma unroll
    for (int nt = 0; nt < 8; ++nt)
#pragma unroll
        for (int r = 0; r < 4; ++r) {
            int rr = r0 + w * 16 + q * 4 + r;
            if (rr < n)
                H1b[(size_t)rr * 128 + nt * 16 + ml] = bf1(acc[nt][r]);
        }
}

// h2b[n,64](bf16) = h(bf16) @ W2. Same structure, N=64.
__global__ __launch_bounds__(256) void k_gemm2(const unsigned* __restrict__ Hin,
                                               const unsigned short* __restrict__ Wt,
                                               unsigned short* __restrict__ H2b, int n) {
    __shared__ unsigned short xs[64][136];
    __shared__ unsigned short wt[64][136];
    int tid = threadIdx.x;
    int r0 = blockIdx.x * 64;

    for (int i = tid; i < 64 * 16; i += 256) {
        int r = i >> 4, c = i & 15;
        uint4 v = make_uint4(0u, 0u, 0u, 0u);
        if (r0 + r < n) v = ((const uint4*)Hin)[(size_t)(r0 + r) * 16 + c];
        *(uint4*)&xs[r][c * 8] = v;
    }
    for (int i = tid; i < 64 * 16; i += 256) {
        int r = i >> 4, c = i & 15;
        *(uint4*)&wt[r][c * 8] = ((const uint4*)Wt)[r * 16 + c];
    }
    __syncthreads();

    int w = tid >> 6, lane = tid & 63;
    int ml = lane & 15, q = lane >> 4;
    floatx4 acc[4];
#pragma unroll
    for (int t = 0; t < 4; ++t) acc[t] = (floatx4)(0.f);

#pragma unroll
    for (int kc = 0; kc < 4; ++kc) {
        short8 af = *(const short8*)&xs[w * 16 + ml][kc * 32 + q * 8];
#pragma unroll
        for (int nt = 0; nt < 4; ++nt) {
            short8 bf = *(const short8*)&wt[nt * 16 + ml][kc * 32 + q * 8];
            acc[nt] = __builtin_amdgcn_mfma_f32_16x16x32_bf16(af, bf, acc[nt], 0, 0, 0);
        }
    }
#pragma unroll
    for (int nt = 0; nt < 4; ++nt)
#pragma unroll
        for (int r = 0; r < 4; ++r) {
            int rr = r0 + w * 16 + q * 4 + r;
            if (rr < n)
                H2b[(size_t)rr * 64 + nt * 16 + ml] = bf1(acc[nt][r]);
        }
}

// ---------------- Aggregations ----------------

// agg1: h[row](bf16) = relu((1/deg) * sum h1b[c]), D=128.
__global__ __launch_bounds__(256) void k_agg1(const unsigned* __restrict__ H1b,
                                              const int* __restrict__ offs,
                                              const int* __restrict__ degc,
                                              const float* __restrict__ invdeg,
                                              const int* __restrict__ csr,
                                              unsigned* __restrict__ Hout, int n) {
    int wave = threadIdx.x >> 6, lane = threadIdx.x & 63;
    int row = blockIdx.x * 4 + wave;
    if (row >= n) return;
    int start = offs[row], d = degc[row];
    float s0[8], s1[8];
#pragma unroll
    for (int j = 0; j < 8; ++j) { s0[j] = 0.f; s1[j] = 0.f; }
    int i = 0;
    for (; i + 8 <= d; i += 8) {
        int idx[8];
#pragma unroll
        for (int j = 0; j < 8; ++j) idx[j] = csr[start + i + j];
        unsigned v[8];
#pragma unroll
        for (int j = 0; j < 8; ++j) v[j] = H1b[(size_t)idx[j] * 64 + lane];
#pragma unroll
        for (int j = 0; j < 8; ++j) {
            s0[j] += __uint_as_float(v[j] << 16);
            s1[j] += __uint_as_float(v[j] & 0xffff0000u);
        }
    }
    for (; i < d; ++i) {
        int c = csr[start + i];
        unsigned v = H1b[(size_t)c * 64 + lane];
        s0[0] += __uint_as_float(v << 16);
        s1[0] += __uint_as_float(v & 0xffff0000u);
    }
    float t0 = (s0[0] + s0[1]) + (s0[2] + s0[3]) + ((s0[4] + s0[5]) + (s0[6] + s0[7]));
    float t1 = (s1[0] + s1[1]) + (s1[2] + s1[3]) + ((s1[4] + s1[5]) + (s1[6] + s1[7]));
    float inv = invdeg[row];
    t0 = fmaxf(t0 * inv, 0.f);
    t1 = fmaxf(t1 * inv, 0.f);
    Hout[(size_t)row * 64 + lane] = bfpack(t0, t1);
}

// agg2: Out[row](fp32) = (1/deg) * sum h2b[c], D=64.
__global__ __launch_bounds__(256) void k_agg2(const unsigned short* __restrict__ H2b,
                                              const int* __restrict__ offs,
                                              const int* __restrict__ degc,
                                              const float* __restrict__ invdeg,
                                              const int* __restrict__ csr,
                                              float* __restrict__ Out, int n) {
    int wave = threadIdx.x >> 6, lane = threadIdx.x & 63;
    int row = blockIdx.x * 4 + wave;
    if (row >= n) return;
    int start = offs[row], d = degc[row];
    float s[8];
#pragma unroll
    for (int j = 0; j < 8; ++j) s[j] = 0.f;
    int i = 0;
    for (; i + 8 <= d; i += 8) {
        int idx[8];
#pragma unroll
        for (int j = 0; j < 8; ++j) idx[j] = csr[start + i + j];
        unsigned short v[8];
#pragma unroll
        for (int j = 0; j < 8; ++j) v[j] = H2b[(size_t)idx[j] * 64 + lane];
#pragma unroll
        for (int j = 0; j < 8; ++j)
            s[j] += __uint_as_float(((unsigned)v[j]) << 16);
    }
    for (; i < d; ++i) {
        int c = csr[start + i];
        s[0] += __uint_as_float(((unsigned)H2b[(size_t)c * 64 + lane]) << 16);
    }
    float t = (s[0] + s[1]) + (s[2] + s[3]) + ((s[4] + s[5]) + (s[6] + s[7]));
    Out[(size_t)row * 64 + lane] = t * invdeg[row];
}

extern "C" void kernel_launch(void* const* d_in, const int* in_sizes, int n_in,
                              void* d_out, int out_size, void* d_ws, size_t ws_size,
                              hipStream_t stream) {
    const float* x    = (const float*)d_in[0];
    const float* W1   = (const float*)d_in[1];
    const float* W2   = (const float*)d_in[2];
    const int*   erow = (const int*)d_in[3];
    const int*   ecol = (const int*)d_in[4];
    const int N = in_sizes[0] / DIN;
    const int E = in_sizes[3];

    const int nb  = (N + (1 << BSH) - 1) >> BSH;   // 196 buckets
    const int nch = (E + CHUNK - 1) / CHUNK;       // 391 chunks

    size_t o = 0;
    auto take = [&](size_t nbytes) {
        void* p = (char*)d_ws + o;
        o += (nbytes + 255) & ~(size_t)255;
        return p;
    };
    int*            HT     = (int*)take((size_t)nb * nch * 4);
    int*            bsum   = (int*)take((size_t)nb * 4);
    int*            bbase  = (int*)take((size_t)(nb + 1) * 4);
    int*            packed = (int*)take((size_t)E * 4);
    int*            csr    = (int*)take((size_t)E * 4);
    int*            offs   = (int*)take((size_t)N * 4);
    int*            degc   = (int*)take((size_t)N * 4);
    float*          invdeg = (float*)take((size_t)N * 4);
    unsigned short* Wt1    = (unsigned short*)take(128 * 128 * 2);
    unsigned short* Wt2    = (unsigned short*)take(64 * 128 * 2);
    unsigned*       h1b    = (unsigned*)take((size_t)N * DH * 2);   // bf16
    unsigned*       h      = (unsigned*)take((size_t)N * DH * 2);   // bf16
    unsigned*       h2b    = h1b;   // reuses h1b (dead after agg1)

    k_prep      <<<96,  256, 0, stream>>>(W1, W2, Wt1, Wt2);
    k_hist      <<<nch, 256, 0, stream>>>(erow, HT, E, nb, nch);
    k_hscan_row <<<nb,  256, 0, stream>>>(HT, bsum, nch);
    k_hscan_base<<<1,   256, 0, stream>>>(bsum, bbase, nb, E);
    k_part      <<<nch, 256, 0, stream>>>(erow, ecol, HT, bbase, packed, E, nb, nch);
    k_build     <<<nb,  256, 0, stream>>>(packed, bbase, csr, offs, degc, invdeg, N, nb);
    k_gemm1<<<(N + 63) / 64, 256, 0, stream>>>(x, Wt1, (unsigned short*)h1b, N);
    k_agg1 <<<(N + 3) / 4, 256, 0, stream>>>(h1b, offs, degc, invdeg, csr, h, N);
    k_gemm2<<<(N + 63) / 64, 256, 0, stream>>>(h, Wt2, (unsigned short*)h2b, N);
    k_agg2 <<<(N + 3) / 4, 256, 0, stream>>>((const unsigned short*)h2b, offs, degc,
                                             invdeg, csr, (float*)d_out, N);
}